// Round 12
// baseline (277.619 us; speedup 1.0000x reference)
//
#include <hip/hip_runtime.h>
#include <cstdint>
#include <cstddef>

typedef unsigned short u16;
typedef unsigned int   u32;
typedef __bf16  bf16x8 __attribute__((ext_vector_type(8)));
typedef float   f32x4  __attribute__((ext_vector_type(4)));

#define B_    2
#define N_    1024
#define K_    48
#define H_    128
#define CAT_  384
#define FF_   512
#define YPAD  136   // bf16 row pitch for 128-col tiles (128+8)
#define HIDP  520   // bf16 row pitch for ffn hid tile (512+8)
#define MPAD  132   // fp32 row pitch for 128-col fp32 tiles
#define MSP   68    // fp32 row pitch for 64-col M half-tiles (edge)
#define XAP   264   // node X-tile pitch (256+8)
#define EPS_  1e-5f
#define INV_SCALE (1.0f/48.0f)

__device__ __forceinline__ float bf2f(u16 u){ u32 x=((u32)u)<<16; float f; __builtin_memcpy(&f,&x,4); return f; }
__device__ __forceinline__ u16 f2bf(float f){ u32 x; __builtin_memcpy(&x,&f,4); x=(x+0x7FFFu+((x>>16)&1u))>>16; return (u16)x; }
__device__ __forceinline__ u32 pk2(float lo, float hi){ return (u32)f2bf(lo) | ((u32)f2bf(hi)<<16); }

// Branch-free exact-GELU: erf via Abramowitz-Stegun 7.1.26 (|err|<=1.5e-7).
__device__ __forceinline__ float gelu_ex(float x){
    const float s = x * 0.7071067811865476f;
    const float a = fabsf(s);
    const float t = __builtin_amdgcn_rcpf(__builtin_fmaf(0.3275911f, a, 1.0f));
    float p = __builtin_fmaf(1.061405429f, t, -1.453152027f);
    p = __builtin_fmaf(p, t,  1.421413741f);
    p = __builtin_fmaf(p, t, -0.284496736f);
    p = __builtin_fmaf(p, t,  0.254829592f);
    p *= t;
    const float e = __expf(-s*s);
    const float erfa = __builtin_fmaf(-p, e, 1.0f);
    const float erf  = __builtin_copysignf(erfa, s);
    return 0.5f*x*(1.0f+erf);
}
__device__ __forceinline__ f32x4 fzero(){ f32x4 v; v[0]=0.f; v[1]=0.f; v[2]=0.f; v[3]=0.f; return v; }

__device__ __forceinline__ float ldf(const void* p, size_t i, int bf){
    return bf ? bf2f(((const u16*)p)[i]) : ((const float*)p)[i];
}
// 8 consecutive elems -> bf16 LDS (dtype-aware)
__device__ __forceinline__ void cp8(u16* dst, const void* src, size_t eoff, int bf){
    if (bf) { *(uint4*)dst = *(const uint4*)((const u16*)src + eoff); }
    else {
        const float4* s = (const float4*)((const float*)src + eoff);
        float4 a = s[0], b = s[1];
        uint4 o; o.x = pk2(a.x,a.y); o.y = pk2(a.z,a.w); o.z = pk2(b.x,b.y); o.w = pk2(b.z,b.w);
        *(uint4*)dst = o;
    }
}

// ---------------- parallel dtype probes (R12: the serial 128-iter thread-0
// scans put 4-8 µs of dependent-load latency in EVERY mega_prep block; the
// int64-index probe never early-exits. Same decision logic, 128-wide.) -------
__device__ __forceinline__ int probe_f_par(const void* p, int n_elems, int tid,
                                           volatile int* s_spec, volatile int* s_nb)
{
    if (tid == 0) {
        const u32 w0 = ((const u32*)p)[0];
        *s_spec = (w0 == 0x3F803F80u) ? 1 : ((w0 == 0x3F800000u) ? 0 : -1);
        *s_nb = 0;
    }
    __syncthreads();
    int sp = *s_spec;
    if (sp < 0) {
        const int m = n_elems < 128 ? n_elems : 128;
        if (tid < m) {
            float v = fabsf(bf2f(((const u16*)p)[tid]));
            if (v > 1e6f) *s_nb = 1;
        }
        __syncthreads();
        sp = (*s_nb) ? 0 : 1;
    }
    __syncthreads();          // shared ints reusable by a subsequent probe
    return sp;
}
__device__ __forceinline__ int probe_i_par(const int* p, int tid, volatile int* s_nb)
{
    if (tid == 0) *s_nb = 0;
    __syncthreads();
    if (tid < 128) { if (((const u32*)p)[2*tid+1] != 0u) *s_nb = 1; }
    __syncthreads();
    const int r = (*s_nb) ? 0 : 1;
    __syncthreads();
    return r;
}
struct Ptrs27 { const void* p[27]; int n[27]; };

// ================= mega_prep: repacks + idx + probes + gv1 in ONE launch =================
// Block map: repack 0..71 (64x64 transpose tiles), prep_idx 72..455,
// probes 456..482, gv1 483..610.
// R12: pre_gv1 folded in — its blocks self-stage bf16(W1[0:128,:])^T into LDS
// (same f2bf rounding as the repack -> bitwise-identical gv1f), which severs
// the w1t dependency and removes one launch + its gap.
__global__ void __launch_bounds__(256)
mega_prep(Ptrs27 P, u16* __restrict__ ws, int* __restrict__ flags, float* __restrict__ gv1f)
{
    // ws layout (u16 units) — must match kernel_launch
    u16* w1t   = ws;
    u16* w2t   = w1t   + 128*384;
    u16* w3t   = w2t   + 128*128;
    u16* w11t  = w3t   + 128*128;
    u16* w12t  = w11t  + 128*384;
    u16* w13t  = w12t  + 128*128;
    u16* wintt = w13t  + 128*128;
    u16* woutt = wintt + 512*128;
    int* idxn  = (int*)(woutt + 128*512);

    __shared__ int s_spec, s_nb;
    __shared__ __align__(16) u16 smem[144*136];   // 39,168 B: gv1 uses all; repack uses 64x65
    const int blk = blockIdx.x;
    const int tid = threadIdx.x;

    if (blk >= 483) {                  // ---- gv1 job: 128 blocks ----
        const int r0g = (blk - 483) * 16;
        const int fHV = probe_f_par(P.p[0], P.n[0], tid, &s_spec, &s_nb);
        const int fW1 = probe_f_par(P.p[5], P.n[5], tid, &s_spec, &s_nb);
        const int fb1 = probe_f_par(P.p[6], P.n[6], tid, &s_spec, &s_nb);
        u16* Wt = smem;                 // [128][136] bf16 W1-top^T
        u16* Ah = smem + 128*136;       // [16][136]  bf16 hV rows
        {   // stage Ah: 16 rows x 128 cols, one cp8 per thread
            const int row = tid >> 4, c8 = (tid & 15) << 3;
            cp8(&Ah[row*136 + c8], P.p[0], (size_t)(r0g+row)*H_ + c8, fHV);
        }
        {   // stage Wt: Wt[n][k] = bf16(W1[k][n]), coalesced reads, LDS scatter
            const void* w1src = P.p[5];
            for (int e = tid; e < 128*128; e += 256) {
                const int k = e >> 7, n = e & 127;
                Wt[n*136 + k] = fW1 ? ((const u16*)w1src)[k*128 + n]
                                    : f2bf(((const float*)w1src)[(size_t)k*128 + n]);
            }
        }
        __syncthreads();
        const int lane = tid & 63, w = tid >> 6;
        const int l15 = lane & 15, q = lane >> 4;
        const int n0 = w*32;
        f32x4 a0v, a1v;
        { float b0v = ldf(P.p[6], n0+l15, fb1), b1v = ldf(P.p[6], n0+16+l15, fb1);
          for (int r=0;r<4;r++){ a0v[r]=b0v; a1v[r]=b1v; } }
#pragma unroll 1
        for (int k0 = 0; k0 < H_; k0 += 32) {
            const int ko = k0 + q*8;
            bf16x8 a  = *(const bf16x8*)&Ah[l15*136 + ko];
            bf16x8 b0 = *(const bf16x8*)&Wt[(n0 + l15)*136 + ko];
            bf16x8 b1 = *(const bf16x8*)&Wt[(n0 + 16 + l15)*136 + ko];
            a0v = __builtin_amdgcn_mfma_f32_16x16x32_bf16(a,b0,a0v,0,0,0);
            a1v = __builtin_amdgcn_mfma_f32_16x16x32_bf16(a,b1,a1v,0,0,0);
        }
        for (int r=0;r<4;r++) {
            gv1f[(size_t)(r0g + q*4 + r)*H_ + n0 + l15]      = a0v[r];
            gv1f[(size_t)(r0g + q*4 + r)*H_ + n0 + 16 + l15] = a1v[r];
        }
        return;
    }
    if (blk >= 456) {                  // ---- probe job: 27 blocks ----
        const int t = blk - 456;
        const int r = (t == 2) ? probe_i_par((const int*)P.p[t], tid, &s_nb)
                               : probe_f_par(P.p[t], P.n[t], tid, &s_spec, &s_nb);
        if (tid == 0) flags[t] = r;
        return;
    }
    if (blk >= 72) {                   // ---- prep_idx: 384 blocks ----
        const int* s = (const int*)P.p[2];
        const int w64 = probe_i_par(s, tid, &s_nb);
        const int i = (blk - 72)*256 + tid;
        if (i < B_*N_*K_) idxn[i] = w64 ? s[2*i] : s[i];
        return;
    }
    // ---- weight repack: [ri][co] -> bf16 [co][ri], one 64x64 tile per block ----
    u16 (*tile)[65] = (u16(*)[65])smem;   // 64x65: 2-way max bank aliasing (free)
    const void* src; u16* dst; int ri, co, rel;
    if      (blk < 12) { src=P.p[5];  dst=w1t;   ri=384; co=128; rel=blk;     }
    else if (blk < 16) { src=P.p[7];  dst=w2t;   ri=128; co=128; rel=blk-12;  }
    else if (blk < 20) { src=P.p[9];  dst=w3t;   ri=128; co=128; rel=blk-16;  }
    else if (blk < 32) { src=P.p[11]; dst=w11t;  ri=384; co=128; rel=blk-20;  }
    else if (blk < 36) { src=P.p[13]; dst=w12t;  ri=128; co=128; rel=blk-32;  }
    else if (blk < 40) { src=P.p[15]; dst=w13t;  ri=128; co=128; rel=blk-36;  }
    else if (blk < 56) { src=P.p[17]; dst=wintt; ri=128; co=512; rel=blk-40;  }
    else               { src=P.p[19]; dst=woutt; ri=512; co=128; rel=blk-56;  }
    const int bf = probe_f_par(src, 128, tid, &s_spec, &s_nb);
    const int tc = co >> 6;
    const int r0 = (rel / tc) * 64, o0 = (rel % tc) * 64;
    const int lr = tid >> 6, lc = tid & 63;
#pragma unroll
    for (int pph = 0; pph < 16; pph++) {
        const int row = pph*4 + lr;
        tile[row][lc] = bf ? ((const u16*)src)[(size_t)(r0+row)*co + o0 + lc]
                           : f2bf(((const float*)src)[(size_t)(r0+row)*co + o0 + lc]);
    }
    __syncthreads();
#pragma unroll
    for (int pph = 0; pph < 16; pph++) {
        const int o = pph*4 + lr;
        dst[(size_t)(o0+o)*ri + r0 + lc] = tile[lc][o];   // contiguous u16 over lc
    }
}

// ---- single-column-block GEMM pass (register-pressure-reduced) ----
// acc must be statically indexed at call sites (rule #20; R4 post-mortem).
// k-loop unroll BOUNDED at 2 (R10/R11): full unroll hoisted fragment loads over
// the (256,4) 128-reg cap -> ~26 MB/dispatch scratch spill.
template<int KD, int AP, int LD, int KOFF>
__device__ __forceinline__ void mfma3x1(const u16* As, const u16* __restrict__ wt, int tid, int ct, f32x4 acc[3])
{
    const int lane = tid & 63;
    const int l15  = lane & 15, q = lane >> 4;
    const int n0   = (tid >> 6) * 32 + ct*16;
#pragma unroll 2
    for (int k0 = 0; k0 < KD; k0 += 32) {
        const int ko = k0 + q*8;
        bf16x8 b0 = *(const bf16x8*)&wt[(size_t)(n0 + l15)*LD + KOFF + ko];
        bf16x8 a0 = *(const bf16x8*)&As[(l15     )*AP + ko];
        bf16x8 a1 = *(const bf16x8*)&As[(l15 + 16)*AP + ko];
        bf16x8 a2 = *(const bf16x8*)&As[(l15 + 32)*AP + ko];
        acc[0] = __builtin_amdgcn_mfma_f32_16x16x32_bf16(a0,b0,acc[0],0,0,0);
        acc[1] = __builtin_amdgcn_mfma_f32_16x16x32_bf16(a1,b0,acc[1],0,0,0);
        acc[2] = __builtin_amdgcn_mfma_f32_16x16x32_bf16(a2,b0,acc[2],0,0,0);
    }
}
// D[row=mt*16+(lane>>4)*4+r][col=(wave*32)+ct*16+(lane&15)]  (m89-verified C/D mapping)
template<bool BIAS>
__device__ __forceinline__ void epi_gelu1(const f32x4 acc[3], const void* __restrict__ bias, int bf,
                                          u16* Outs, int tid, int ct)
{
    const int lane = tid & 63, l15 = lane & 15, q = lane >> 4;
    const int col = (tid>>6)*32 + ct*16 + l15;
    float bv = 0.f;
    if constexpr (BIAS) bv = ldf(bias, col, bf);
    for (int mt = 0; mt < 3; mt++)
        for (int r = 0; r < 4; r++)
            Outs[(mt*16 + q*4 + r)*YPAD + col] = f2bf(gelu_ex(acc[mt][r] + bv));
}

// ================= node kernel: message + LN1 only =================
__global__ void __launch_bounds__(256, 4)
node_mfma(const void* __restrict__ hV, const void* __restrict__ hE, const int* __restrict__ idxn,
          const void* __restrict__ maskAtt,
          const u16* __restrict__ w1t,
          const u16* __restrict__ w2t, const void* __restrict__ b2,
          const u16* __restrict__ w3t, const void* __restrict__ b3,
          const void* __restrict__ g1, const void* __restrict__ be1,
          const float* __restrict__ gv1f,
          const int* __restrict__ flags,
          float* __restrict__ hvn1f)
{
    __shared__ __align__(16) u16 Xs[K_*XAP];     // X tile; later aliased as Y2
    __shared__ __align__(16) u16 Y1s[K_*YPAD];
    __shared__ float dhs[H_];
    __shared__ float matt[K_];
    __shared__ int   idxs[K_];
    __shared__ float stats[3];                   // mean, rstd, summask

    const int bn  = blockIdx.x;
    const int b   = bn >> 10;
    const int tid = threadIdx.x;
    const int lane = tid & 63, w = tid >> 6;

    const int fHV = flags[0], fHE = flags[1], fMA = flags[4];
    const int fb2 = flags[8], fb3 = flags[10];
    const int fg1 = flags[21], fbe1 = flags[22];

    if (tid < K_) { idxs[tid] = idxn[bn*K_ + tid]; matt[tid] = ldf(maskAtt, (size_t)bn*K_ + tid, fMA); }
    __syncthreads();
    if (tid == 0) { float s=0.f; for (int k=0;k<K_;k++) s += matt[k]; stats[2] = s; }

    for (int u = tid; u < 768; u += 256) {
        const int row = u >> 4, c8 = (u & 15) << 3;
        cp8(&Xs[row*XAP + c8],      hE, ((size_t)bn*K_ + row)*H_ + c8, fHE);
        cp8(&Xs[row*XAP + H_ + c8], hV, ((size_t)b*N_ + idxs[row])*H_ + c8, fHV);
    }
    __syncthreads();

    const int l15 = lane & 15, q = lane >> 4, n0 = w*32;

    // ---- GEMM1: C-init from gv1 (center term + b1, precomputed) ----
#pragma unroll 1
    for (int ct = 0; ct < 2; ct++) {
        f32x4 acc[3];
        const float g = gv1f[(size_t)bn*H_ + n0 + ct*16 + l15];
        for (int mt=0; mt<3; mt++) for (int r=0; r<4; r++) acc[mt][r] = g;
        mfma3x1<256, XAP, CAT_, H_>(Xs, w1t, tid, ct, acc);   // W1 rows 128..383
        epi_gelu1<false>(acc, nullptr, 0, Y1s, tid, ct);
    }
    __syncthreads();

    u16* Y2s = Xs;
#pragma unroll 1
    for (int ct = 0; ct < 2; ct++) {
        f32x4 acc[3] = {fzero(), fzero(), fzero()};
        mfma3x1<H_, YPAD, H_, 0>(Y1s, w2t, tid, ct, acc);
        epi_gelu1<true>(acc, b2, fb2, Y2s, tid, ct);
    }
    __syncthreads();

#pragma unroll 1
    for (int ct = 0; ct < 2; ct++) {
        f32x4 acc[3] = {fzero(), fzero(), fzero()};
        mfma3x1<H_, YPAD, H_, 0>(Y2s, w3t, tid, ct, acc);
        float s0 = 0.f;
        for (int mt=0; mt<3; mt++)
            for (int r=0; r<4; r++)
                s0 += acc[mt][r]*matt[mt*16 + q*4 + r];
        s0 += __shfl_xor(s0,16); s0 += __shfl_xor(s0,32);
        if (q == 0) {
            const int col = n0 + ct*16 + l15;
            dhs[col] = (s0 + ldf(b3, col, fb3)*stats[2]) * INV_SCALE;
        }
    }
    __syncthreads();

    // ---- LN1 -> hvn1f (fp32 ws; ffn_fused consumes) ----
    if (w == 0) {
        float a = ldf(hV, (size_t)bn*H_ + lane,      fHV) + dhs[lane];
        float c = ldf(hV, (size_t)bn*H_ + lane + 64, fHV) + dhs[lane+64];
        float s = a + c, ss = a*a + c*c;
        for (int off=32; off>0; off>>=1) { s += __shfl_xor(s,off); ss += __shfl_xor(ss,off); }
        if (lane == 0) { float m = s*(1.f/H_); stats[0]=m; stats[1]=rsqrtf(ss*(1.f/H_)-m*m+EPS_); }
    }
    __syncthreads();
    if (tid < H_) {
        float h = ldf(hV, (size_t)bn*H_ + tid, fHV) + dhs[tid];
        hvn1f[(size_t)bn*H_ + tid] = (h - stats[0])*stats[1]*ldf(g1,tid,fg1) + ldf(be1,tid,fbe1);
    }
}

// ================= ffn_fused: FFN + LN2 + mask + gv11, 16 rows/block =================
__global__ void __launch_bounds__(256, 2)
ffn_fused(const float* __restrict__ hvn1f, const void* __restrict__ maskV,
          const u16* __restrict__ wintt, const void* __restrict__ bin,
          const u16* __restrict__ woutt, const void* __restrict__ bout,
          const u16* __restrict__ w11t, const void* __restrict__ b11,
          const void* __restrict__ g2, const void* __restrict__ be2,
          const int* __restrict__ flags,
          float* __restrict__ outV, u16* __restrict__ wsVn, float* __restrict__ gv11f)
{
    __shared__ __align__(16) float hvf[16*H_];     // fp32 hvn1 (residual)
    __shared__ __align__(16) u16   Xh[16*YPAD];    // bf16 A-tile of hvn1
    __shared__ __align__(16) u16   hid[16*HIDP];   // bf16 hidden 16x512
    __shared__ __align__(16) float h2f[16*MPAD];   // fp32 pre-LN2
    __shared__ __align__(16) u16   h2b[16*YPAD];   // bf16 LN2 out (gv11 A-tile)

    const int r0  = blockIdx.x*16;
    const int tid = threadIdx.x, lane = tid & 63, w = tid >> 6;
    const int l15 = lane & 15, q = lane >> 4;
    const int fMV = flags[3], fbin = flags[18], fbout = flags[20];
    const int fb11 = flags[12], fg2 = flags[23], fbe2 = flags[24];

    {   // stage hvn1 rows (fp32 + bf16)
        const int row = tid >> 4, c8 = (tid & 15) << 3;
        const float4* s = (const float4*)&hvn1f[(size_t)(r0+row)*H_ + c8];
        float4 a = s[0], b = s[1];
        *(float4*)&hvf[row*H_ + c8]     = a;
        *(float4*)&hvf[row*H_ + c8 + 4] = b;
        uint4 o; o.x = pk2(a.x,a.y); o.y = pk2(a.z,a.w); o.z = pk2(b.x,b.y); o.w = pk2(b.z,b.w);
        *(uint4*)&Xh[row*YPAD + c8] = o;
    }
    __syncthreads();

    // ---- GEMM1: hid[16x512]; wave w owns cols w*128..+127 (8 ct blocks) ----
    {
        f32x4 acc[8];
#pragma unroll
        for (int ct = 0; ct < 8; ct++) {
            const float bv = ldf(bin, w*128 + ct*16 + l15, fbin);
            for (int r=0;r<4;r++) acc[ct][r] = bv;
        }
#pragma unroll 1
        for (int k0 = 0; k0 < H_; k0 += 32) {
            const int ko = k0 + q*8;
            bf16x8 a = *(const bf16x8*)&Xh[l15*YPAD + ko];
#pragma unroll
            for (int ct = 0; ct < 8; ct++) {
                bf16x8 b = *(const bf16x8*)&wintt[(size_t)(w*128 + ct*16 + l15)*H_ + ko];
                acc[ct] = __builtin_amdgcn_mfma_f32_16x16x32_bf16(a,b,acc[ct],0,0,0);
            }
        }
#pragma unroll
        for (int ct = 0; ct < 8; ct++) {
            const int col = w*128 + ct*16 + l15;
            for (int r=0;r<4;r++)
                hid[(q*4 + r)*HIDP + col] = f2bf(gelu_ex(acc[ct][r]));
        }
    }
    __syncthreads();

    // ---- GEMM2: out 16x128; wave w owns 32 cols; + bout + fp32 residual ----
    {
        const int n0 = w*32;
        f32x4 c0 = fzero(), c1 = fzero();
#pragma unroll 1
        for (int k0 = 0; k0 < FF_; k0 += 32) {
            const int ko = k0 + q*8;
            bf16x8 a  = *(const bf16x8*)&hid[l15*HIDP + ko];
            bf16x8 b0 = *(const bf16x8*)&woutt[(size_t)(n0 + l15)*FF_ + ko];
            bf16x8 b1 = *(const bf16x8*)&woutt[(size_t)(n0 + 16 + l15)*FF_ + ko];
            c0 = __builtin_amdgcn_mfma_f32_16x16x32_bf16(a,b0,c0,0,0,0);
            c1 = __builtin_amdgcn_mfma_f32_16x16x32_bf16(a,b1,c1,0,0,0);
        }
        const float bo0 = ldf(bout, n0+l15, fbout), bo1 = ldf(bout, n0+16+l15, fbout);
        for (int r=0;r<4;r++) {
            const int row = q*4 + r;
            h2f[row*MPAD + n0+l15]    = c0[r] + bo0 + hvf[row*H_ + n0+l15];
            h2f[row*MPAD + n0+16+l15] = c1[r] + bo1 + hvf[row*H_ + n0+16+l15];
        }
    }
    __syncthreads();

    // ---- LN2 + mask; rows w, w+4, w+8, w+12 per wave ----
    for (int row = w; row < 16; row += 4) {
        float v0 = h2f[row*MPAD + lane], v1 = h2f[row*MPAD + lane + 64];
        float s = v0+v1, ss = v0*v0+v1*v1;
        for (int off=32; off>0; off>>=1) { s += __shfl_xor(s,off); ss += __shfl_xor(ss,off); }
        const float m = s*(1.f/H_);
        const float rstd = rsqrtf(ss*(1.f/H_) - m*m + EPS_);
        const float mk = ldf(maskV, r0+row, fMV);
        const float o0 = ((v0-m)*rstd*ldf(g2,lane,fg2)    + ldf(be2,lane,fbe2))    * mk;
        const float o1 = ((v1-m)*rstd*ldf(g2,lane+64,fg2) + ldf(be2,lane+64,fbe2)) * mk;
        outV[(size_t)(r0+row)*H_ + lane]      = o0;
        outV[(size_t)(r0+row)*H_ + lane + 64] = o1;
        const u16 u0 = f2bf(o0), u1 = f2bf(o1);
        wsVn[(size_t)(r0+row)*H_ + lane]      = u0;
        wsVn[(size_t)(r0+row)*H_ + lane + 64] = u1;
        h2b[row*YPAD + lane]      = u0;
        h2b[row*YPAD + lane + 64] = u1;
    }
    __syncthreads();

    // ---- GEMM3: gv11 = h2b @ W11[0:128,:] + b11 (edge center term) ----
    {
        const int n0 = w*32;
        f32x4 d0, d1;
        { float b0v = ldf(b11, n0+l15, fb11), b1v = ldf(b11, n0+16+l15, fb11);
          for (int r=0;r<4;r++){ d0[r]=b0v; d1[r]=b1v; } }
#pragma unroll 1
        for (int k0 = 0; k0 < H_; k0 += 32) {
            const int ko = k0 + q*8;
            bf16x8 a  = *(const bf16x8*)&h2b[l15*YPAD + ko];
            bf16x8 b0 = *(const bf16x8*)&w11t[(size_t)(n0 + l15)*CAT_ + ko];
            bf16x8 b1 = *(const bf16x8*)&w11t[(size_t)(n0 + 16 + l15)*CAT_ + ko];
            d0 = __builtin_amdgcn_mfma_f32_16x16x32_bf16(a,b0,d0,0,0,0);
            d1 = __builtin_amdgcn_mfma_f32_16x16x32_bf16(a,b1,d1,0,0,0);
        }
        for (int r=0;r<4;r++) {
            gv11f[(size_t)(r0 + q*4 + r)*H_ + n0 + l15]      = d0[r];
            gv11f[(size_t)(r0 + q*4 + r)*H_ + n0 + 16 + l15] = d1[r];
        }
    }
}

// ================= edge kernel: MFMA =================
// (256,4) + Ms half-tile split (R8) + preserved hEs tile (R10) + bounded
// mfma3x1 unroll (R11, spill fix).
__global__ void __launch_bounds__(256, 4)
edge_mfma(const u16* __restrict__ wsVn, const void* __restrict__ hE, const int* __restrict__ idxn,
          const u16* __restrict__ w11t,
          const u16* __restrict__ w12t, const void* __restrict__ b12,
          const u16* __restrict__ w13t, const void* __restrict__ b13,
          const void* __restrict__ g3, const void* __restrict__ be3,
          const float* __restrict__ gv11f,
          const int* __restrict__ flags,
          float* __restrict__ outE)
{
    __shared__ __align__(16) u16 hEs[K_*YPAD];    // hE tile (bf16) — preserved through LN
    __shared__ __align__(16) u16 hvnbs[K_*YPAD];  // hv_nb tile; aliased as Y2, then Ms1
    __shared__ __align__(16) u16 Y1s[K_*YPAD];    // Y1 tile; aliased as Ms0
    __shared__ int idxs[K_];

    const int bn  = blockIdx.x;
    const int b   = bn >> 10;
    const int tid = threadIdx.x;
    const int lane = tid & 63, w = tid >> 6;

    const int fHE = flags[1];
    const int fb12 = flags[14], fb13 = flags[16];
    const int fg3 = flags[25], fbe3 = flags[26];

    if (tid < K_) idxs[tid] = idxn[bn*K_ + tid];
    __syncthreads();

    const u16* hVb = wsVn + (size_t)b*N_*H_;
    for (int u = tid; u < 768; u += 256) {
        const int row = u >> 4, c8 = (u & 15) << 3;
        cp8(&hEs[row*YPAD + c8], hE, ((size_t)bn*K_ + row)*H_ + c8, fHE);
        *(uint4*)&hvnbs[row*YPAD + c8] = *(const uint4*)&hVb[(size_t)idxs[row]*H_ + c8];
    }
    __syncthreads();

    const int l15 = lane & 15, q = lane >> 4, n0 = w*32;

    // GEMM1: C-init from gv11; two half-K passes over the split X tile.
#pragma unroll 1
    for (int ct = 0; ct < 2; ct++) {
        f32x4 acc[3];
        const float g = gv11f[(size_t)bn*H_ + n0 + ct*16 + l15];
        for (int mt=0; mt<3; mt++) for (int r=0; r<4; r++) acc[mt][r] = g;
        mfma3x1<H_, YPAD, CAT_, H_>(hEs,   w11t, tid, ct, acc);   // W11 rows 128..255
        mfma3x1<H_, YPAD, CAT_, 2*H_>(hvnbs, w11t, tid, ct, acc); // W11 rows 256..383
        epi_gelu1<false>(acc, nullptr, 0, Y1s, tid, ct);
    }
    __syncthreads();

    u16* Y2s = hvnbs;                 // hv_nb dead after GEMM1
#pragma unroll 1
    for (int ct = 0; ct < 2; ct++) {
        f32x4 acc[3] = {fzero(), fzero(), fzero()};
        mfma3x1<H_, YPAD, H_, 0>(Y1s, w12t, tid, ct, acc);
        epi_gelu1<true>(acc, b12, fb12, Y2s, tid, ct);
    }
    __syncthreads();                  // Y2 visible; ALL Y1s reads done -> Y1s reusable

    float* Ms0 = (float*)Y1s;         // fp32 [48][MSP], cols c with (c>>4) even
    {
        f32x4 accA[3] = {fzero(), fzero(), fzero()};
        mfma3x1<H_, YPAD, H_, 0>(Y2s, w13t, tid, 0, accA);
        const float bvA = ldf(b13, n0 + l15, fb13);
        const int ci = w*16 + l15;
        for (int mt=0; mt<3; mt++)
            for (int r=0; r<4; r++)
                Ms0[(mt*16 + q*4 + r)*MSP + ci] = accA[mt][r] + bvA;
    }
    {
        f32x4 accB[3] = {fzero(), fzero(), fzero()};
        mfma3x1<H_, YPAD, H_, 0>(Y2s, w13t, tid, 1, accB);
        __syncthreads();              // all Y2 (hvnbs) reads done -> hvnbs reusable
        float* Ms1 = (float*)hvnbs;   // fp32 [48][MSP], cols c with (c>>4) odd
        const float bvB = ldf(b13, n0 + 16 + l15, fb13);
        const int ci = w*16 + l15;
        for (int mt=0; mt<3; mt++)
            for (int r=0; r<4; r++)
                Ms1[(mt*16 + q*4 + r)*MSP + ci] = accB[mt][r] + bvB;
    }
    __syncthreads();                  // Ms0 + Ms1 visible

    // h_En = LN(h_E + M), one wave per row; hE from the PRESERVED LDS tile.
    {
        const float* Ms0c = (const float*)Y1s;
        const float* Ms1c = (const float*)hvnbs;
        const int g0  = lane >> 4;
        const int ci0 = (g0 >> 1)*16 + (lane & 15);   // in-tile col for c=lane
        const int ci1 = ci0 + 32;                     // in-tile col for c=lane+64
        const float* Mt = (g0 & 1) ? Ms1c : Ms0c;
        const float gg0 = ldf(g3, lane, fg3),   gg1 = ldf(g3, lane+64, fg3);
        const float bb0 = ldf(be3, lane, fbe3), bb1 = ldf(be3, lane+64, fbe3);
        for (int row = w; row < K_; row += 4) {
            const size_t e0 = ((size_t)bn*K_ + row)*H_;
            float v0 = bf2f(hEs[row*YPAD + lane])      + Mt[row*MSP + ci0];
            float v1 = bf2f(hEs[row*YPAD + lane + 64]) + Mt[row*MSP + ci1];
            float s = v0+v1, ss = v0*v0+v1*v1;
            for (int off=32; off>0; off>>=1) { s += __shfl_xor(s,off); ss += __shfl_xor(ss,off); }
            const float m = s*(1.f/H_);
            const float rstd = rsqrtf(ss*(1.f/H_) - m*m + EPS_);
            outE[e0 + lane]      = (v0-m)*rstd*gg0 + bb0;
            outE[e0 + lane + 64] = (v1-m)*rstd*gg1 + bb1;
        }
    }
}

extern "C" void kernel_launch(void* const* d_in, const int* in_sizes, int n_in,
                              void* d_out, int out_size, void* d_ws, size_t ws_size,
                              hipStream_t stream)
{
    const void* hV      = d_in[0];
    const void* hE      = d_in[1];
    const void* maskV   = d_in[3];
    const void* maskAtt = d_in[4];
    const void* W2b  = d_in[8];
    const void* W3b  = d_in[10];
    const void* W11b = d_in[12];
    const void* W12b = d_in[14];
    const void* W13b = d_in[16];
    const void* Winb = d_in[18];
    const void* Woutb= d_in[20];
    const void* ln1g = d_in[21]; const void* ln1b = d_in[22];
    const void* ln2g = d_in[23]; const void* ln2b = d_in[24];
    const void* ln3g = d_in[25]; const void* ln3b = d_in[26];

    // ws layout (u16 units) — mirrored inside mega_prep
    u16* ws    = (u16*)d_ws;
    u16* w1t   = ws;                        // 128*384
    u16* w2t   = w1t   + 128*384;           // 128*128
    u16* w3t   = w2t   + 128*128;
    u16* w11t  = w3t   + 128*128;           // 128*384
    u16* w12t  = w11t  + 128*384;
    u16* w13t  = w12t  + 128*128;
    u16* wintt = w13t  + 128*128;           // 512*128
    u16* woutt = wintt + 512*128;           // 128*512
    int* idxn  = (int*)(woutt + 128*512);   // 98304 int32
    u16* wsVn  = (u16*)(idxn + B_*N_*K_);   // 262144 bf16
    float* gv1f  = (float*)(wsVn + B_*N_*H_);   // 262144 f32
    float* hvn1f = gv1f  + (size_t)B_*N_*H_;    // 262144 f32
    float* gv11f = hvn1f + (size_t)B_*N_*H_;    // 262144 f32
    int* flags = (int*)(gv11f + (size_t)B_*N_*H_);  // 27 ints

    Ptrs27 P;
    for (int i = 0; i < 27; i++) { P.p[i] = d_in[i]; P.n[i] = in_sizes[i]; }

    // ONE prep launch: repacks 0..71 + prep_idx 72..455 + probes 456..482 +
    // gv1 (absorbed pre_gv1) 483..610
    hipLaunchKernelGGL(mega_prep, dim3(611), dim3(256), 0, stream, P, ws, flags, gv1f);

    float* outV = (float*)d_out;
    float* outE = outV + (size_t)B_*N_*H_;

    hipLaunchKernelGGL(node_mfma, dim3(B_*N_), dim3(256), 0, stream,
                       hV, hE, idxn, maskAtt,
                       w1t, w2t, W2b, w3t, W3b,
                       ln1g, ln1b, gv1f, flags, hvn1f);
    hipLaunchKernelGGL(ffn_fused, dim3(B_*N_/16), dim3(256), 0, stream,
                       hvn1f, maskV, wintt, Winb, woutt, Woutb,
                       w11t, W11b, ln2g, ln2b, flags, outV, wsVn, gv11f);
    hipLaunchKernelGGL(edge_mfma, dim3(B_*N_), dim3(256), 0, stream,
                       wsVn, hE, idxn,
                       w11t, w12t, W12b, w13t, W13b,
                       ln3g, ln3b, gv11f, flags, outE);
}

// Round 13
// 270.767 us; speedup vs baseline: 1.0253x; 1.0253x over previous
//
#include <hip/hip_runtime.h>
#include <cstdint>
#include <cstddef>

typedef unsigned short u16;
typedef unsigned int   u32;
typedef __bf16  bf16x8 __attribute__((ext_vector_type(8)));
typedef float   f32x4  __attribute__((ext_vector_type(4)));

#define B_    2
#define N_    1024
#define K_    48
#define H_    128
#define CAT_  384
#define FF_   512
#define YPAD  136   // bf16 row pitch for 128-col tiles (128+8)
#define HIDP  520   // bf16 row pitch for ffn hid tile (512+8)
#define MPAD  132   // fp32 row pitch for 128-col fp32 tiles
#define MSP   68    // fp32 row pitch for 64-col M half-tiles (edge)
#define XAP   264   // node X-tile pitch (256+8)
#define EPS_  1e-5f
#define INV_SCALE (1.0f/48.0f)

__device__ __forceinline__ float bf2f(u16 u){ u32 x=((u32)u)<<16; float f; __builtin_memcpy(&f,&x,4); return f; }
__device__ __forceinline__ u16 f2bf(float f){ u32 x; __builtin_memcpy(&x,&f,4); x=(x+0x7FFFu+((x>>16)&1u))>>16; return (u16)x; }
__device__ __forceinline__ u32 pk2(float lo, float hi){ return (u32)f2bf(lo) | ((u32)f2bf(hi)<<16); }

// Branch-free exact-GELU: erf via Abramowitz-Stegun 7.1.26 (|err|<=1.5e-7).
__device__ __forceinline__ float gelu_ex(float x){
    const float s = x * 0.7071067811865476f;
    const float a = fabsf(s);
    const float t = __builtin_amdgcn_rcpf(__builtin_fmaf(0.3275911f, a, 1.0f));
    float p = __builtin_fmaf(1.061405429f, t, -1.453152027f);
    p = __builtin_fmaf(p, t,  1.421413741f);
    p = __builtin_fmaf(p, t, -0.284496736f);
    p = __builtin_fmaf(p, t,  0.254829592f);
    p *= t;
    const float e = __expf(-s*s);
    const float erfa = __builtin_fmaf(-p, e, 1.0f);
    const float erf  = __builtin_copysignf(erfa, s);
    return 0.5f*x*(1.0f+erf);
}
__device__ __forceinline__ f32x4 fzero(){ f32x4 v; v[0]=0.f; v[1]=0.f; v[2]=0.f; v[3]=0.f; return v; }

__device__ __forceinline__ float ldf(const void* p, size_t i, int bf){
    return bf ? bf2f(((const u16*)p)[i]) : ((const float*)p)[i];
}
// 8 consecutive elems -> bf16 LDS (dtype-aware)
__device__ __forceinline__ void cp8(u16* dst, const void* src, size_t eoff, int bf){
    if (bf) { *(uint4*)dst = *(const uint4*)((const u16*)src + eoff); }
    else {
        const float4* s = (const float4*)((const float*)src + eoff);
        float4 a = s[0], b = s[1];
        uint4 o; o.x = pk2(a.x,a.y); o.y = pk2(a.z,a.w); o.z = pk2(b.x,b.y); o.w = pk2(b.z,b.w);
        *(uint4*)dst = o;
    }
}

// ---------------- parallel dtype probes (R12) ----------------
__device__ __forceinline__ int probe_f_par(const void* p, int n_elems, int tid,
                                           volatile int* s_spec, volatile int* s_nb)
{
    if (tid == 0) {
        const u32 w0 = ((const u32*)p)[0];
        *s_spec = (w0 == 0x3F803F80u) ? 1 : ((w0 == 0x3F800000u) ? 0 : -1);
        *s_nb = 0;
    }
    __syncthreads();
    int sp = *s_spec;
    if (sp < 0) {
        const int m = n_elems < 128 ? n_elems : 128;
        if (tid < m) {
            float v = fabsf(bf2f(((const u16*)p)[tid]));
            if (v > 1e6f) *s_nb = 1;
        }
        __syncthreads();
        sp = (*s_nb) ? 0 : 1;
    }
    __syncthreads();
    return sp;
}
__device__ __forceinline__ int probe_i_par(const int* p, int tid, volatile int* s_nb)
{
    if (tid == 0) *s_nb = 0;
    __syncthreads();
    if (tid < 128) { if (((const u32*)p)[2*tid+1] != 0u) *s_nb = 1; }
    __syncthreads();
    const int r = (*s_nb) ? 0 : 1;
    __syncthreads();
    return r;
}
struct Ptrs27 { const void* p[27]; int n[27]; };

// ================= mega_prep: repacks + idx + probes + gv1 in ONE launch =================
// Block map: repack 0..71, prep_idx 72..455, probes 456..482, gv1 483..610. (R12)
__global__ void __launch_bounds__(256)
mega_prep(Ptrs27 P, u16* __restrict__ ws, int* __restrict__ flags, float* __restrict__ gv1f)
{
    // ws layout (u16 units) — must match kernel_launch
    u16* w1t   = ws;
    u16* w2t   = w1t   + 128*384;
    u16* w3t   = w2t   + 128*128;
    u16* w11t  = w3t   + 128*128;
    u16* w12t  = w11t  + 128*384;
    u16* w13t  = w12t  + 128*128;
    u16* wintt = w13t  + 128*128;
    u16* woutt = wintt + 512*128;
    int* idxn  = (int*)(woutt + 128*512);

    __shared__ int s_spec, s_nb;
    __shared__ __align__(16) u16 smem[144*136];
    const int blk = blockIdx.x;
    const int tid = threadIdx.x;

    if (blk >= 483) {                  // ---- gv1 job: 128 blocks ----
        const int r0g = (blk - 483) * 16;
        const int fHV = probe_f_par(P.p[0], P.n[0], tid, &s_spec, &s_nb);
        const int fW1 = probe_f_par(P.p[5], P.n[5], tid, &s_spec, &s_nb);
        const int fb1 = probe_f_par(P.p[6], P.n[6], tid, &s_spec, &s_nb);
        u16* Wt = smem;                 // [128][136] bf16 W1-top^T
        u16* Ah = smem + 128*136;       // [16][136]  bf16 hV rows
        {   const int row = tid >> 4, c8 = (tid & 15) << 3;
            cp8(&Ah[row*136 + c8], P.p[0], (size_t)(r0g+row)*H_ + c8, fHV); }
        {   const void* w1src = P.p[5];
            for (int e = tid; e < 128*128; e += 256) {
                const int k = e >> 7, n = e & 127;
                Wt[n*136 + k] = fW1 ? ((const u16*)w1src)[k*128 + n]
                                    : f2bf(((const float*)w1src)[(size_t)k*128 + n]);
            } }
        __syncthreads();
        const int lane = tid & 63, w = tid >> 6;
        const int l15 = lane & 15, q = lane >> 4;
        const int n0 = w*32;
        f32x4 a0v, a1v;
        { float b0v = ldf(P.p[6], n0+l15, fb1), b1v = ldf(P.p[6], n0+16+l15, fb1);
          for (int r=0;r<4;r++){ a0v[r]=b0v; a1v[r]=b1v; } }
#pragma unroll 1
        for (int k0 = 0; k0 < H_; k0 += 32) {
            const int ko = k0 + q*8;
            bf16x8 a  = *(const bf16x8*)&Ah[l15*136 + ko];
            bf16x8 b0 = *(const bf16x8*)&Wt[(n0 + l15)*136 + ko];
            bf16x8 b1 = *(const bf16x8*)&Wt[(n0 + 16 + l15)*136 + ko];
            a0v = __builtin_amdgcn_mfma_f32_16x16x32_bf16(a,b0,a0v,0,0,0);
            a1v = __builtin_amdgcn_mfma_f32_16x16x32_bf16(a,b1,a1v,0,0,0);
        }
        for (int r=0;r<4;r++) {
            gv1f[(size_t)(r0g + q*4 + r)*H_ + n0 + l15]      = a0v[r];
            gv1f[(size_t)(r0g + q*4 + r)*H_ + n0 + 16 + l15] = a1v[r];
        }
        return;
    }
    if (blk >= 456) {                  // ---- probe job: 27 blocks ----
        const int t = blk - 456;
        const int r = (t == 2) ? probe_i_par((const int*)P.p[t], tid, &s_nb)
                               : probe_f_par(P.p[t], P.n[t], tid, &s_spec, &s_nb);
        if (tid == 0) flags[t] = r;
        return;
    }
    if (blk >= 72) {                   // ---- prep_idx: 384 blocks ----
        const int* s = (const int*)P.p[2];
        const int w64 = probe_i_par(s, tid, &s_nb);
        const int i = (blk - 72)*256 + tid;
        if (i < B_*N_*K_) idxn[i] = w64 ? s[2*i] : s[i];
        return;
    }
    // ---- weight repack: [ri][co] -> bf16 [co][ri], one 64x64 tile per block ----
    u16 (*tile)[65] = (u16(*)[65])smem;
    const void* src; u16* dst; int ri, co, rel;
    if      (blk < 12) { src=P.p[5];  dst=w1t;   ri=384; co=128; rel=blk;     }
    else if (blk < 16) { src=P.p[7];  dst=w2t;   ri=128; co=128; rel=blk-12;  }
    else if (blk < 20) { src=P.p[9];  dst=w3t;   ri=128; co=128; rel=blk-16;  }
    else if (blk < 32) { src=P.p[11]; dst=w11t;  ri=384; co=128; rel=blk-20;  }
    else if (blk < 36) { src=P.p[13]; dst=w12t;  ri=128; co=128; rel=blk-32;  }
    else if (blk < 40) { src=P.p[15]; dst=w13t;  ri=128; co=128; rel=blk-36;  }
    else if (blk < 56) { src=P.p[17]; dst=wintt; ri=128; co=512; rel=blk-40;  }
    else               { src=P.p[19]; dst=woutt; ri=512; co=128; rel=blk-56;  }
    const int bf = probe_f_par(src, 128, tid, &s_spec, &s_nb);
    const int tc = co >> 6;
    const int r0 = (rel / tc) * 64, o0 = (rel % tc) * 64;
    const int lr = tid >> 6, lc = tid & 63;
#pragma unroll
    for (int pph = 0; pph < 16; pph++) {
        const int row = pph*4 + lr;
        tile[row][lc] = bf ? ((const u16*)src)[(size_t)(r0+row)*co + o0 + lc]
                           : f2bf(((const float*)src)[(size_t)(r0+row)*co + o0 + lc]);
    }
    __syncthreads();
#pragma unroll
    for (int pph = 0; pph < 16; pph++) {
        const int o = pph*4 + lr;
        dst[(size_t)(o0+o)*ri + r0 + lc] = tile[lc][o];
    }
}

// ---- single 16-col GEMM pass, wave owns cols n0..n0+15 (R13: 8-wave form) ----
// acc statically indexed at call sites (rule #20). k-loop unroll BOUNDED at 2
// (R10/R11: full unroll spilled at the reg cap).
template<int KD, int AP, int LD, int KOFF>
__device__ __forceinline__ void mfma3w(const u16* As, const u16* __restrict__ wt, int lane, int n0, f32x4 acc[3])
{
    const int l15  = lane & 15, q = lane >> 4;
#pragma unroll 2
    for (int k0 = 0; k0 < KD; k0 += 32) {
        const int ko = k0 + q*8;
        bf16x8 b0 = *(const bf16x8*)&wt[(size_t)(n0 + l15)*LD + KOFF + ko];
        bf16x8 a0 = *(const bf16x8*)&As[(l15     )*AP + ko];
        bf16x8 a1 = *(const bf16x8*)&As[(l15 + 16)*AP + ko];
        bf16x8 a2 = *(const bf16x8*)&As[(l15 + 32)*AP + ko];
        acc[0] = __builtin_amdgcn_mfma_f32_16x16x32_bf16(a0,b0,acc[0],0,0,0);
        acc[1] = __builtin_amdgcn_mfma_f32_16x16x32_bf16(a1,b0,acc[1],0,0,0);
        acc[2] = __builtin_amdgcn_mfma_f32_16x16x32_bf16(a2,b0,acc[2],0,0,0);
    }
}
// D[row=mt*16+(lane>>4)*4+r][col=n0+(lane&15)]  (m89-verified C/D mapping)
template<bool BIAS>
__device__ __forceinline__ void epi_gelu1(const f32x4 acc[3], const void* __restrict__ bias, int bf,
                                          u16* Outs, int lane, int n0)
{
    const int l15 = lane & 15, q = lane >> 4;
    const int col = n0 + l15;
    float bv = 0.f;
    if constexpr (BIAS) bv = ldf(bias, col, bf);
    for (int mt = 0; mt < 3; mt++)
        for (int r = 0; r < 4; r++)
            Outs[(mt*16 + q*4 + r)*YPAD + col] = f2bf(gelu_ex(acc[mt][r] + bv));
}

// ================= node kernel: message + LN1; 512 threads, 8 waves =================
// R13: one 16-col block per wave (was 2 per wave of 4). Halves the per-block
// serial chain; (512,8) -> 4 blocks x 8 waves = 32 waves/CU (100% cap), reg cap
// 64 (current use 52). LDS 39.4KB x4 = 157KB <= 160. Per-column k-order
// unchanged -> bitwise-identical. Spill tripwire: WRITE_SIZE = 1,024 KB.
__global__ void __launch_bounds__(512, 8)
node_mfma(const void* __restrict__ hV, const void* __restrict__ hE, const int* __restrict__ idxn,
          const void* __restrict__ maskAtt,
          const u16* __restrict__ w1t,
          const u16* __restrict__ w2t, const void* __restrict__ b2,
          const u16* __restrict__ w3t, const void* __restrict__ b3,
          const void* __restrict__ g1, const void* __restrict__ be1,
          const float* __restrict__ gv1f,
          const int* __restrict__ flags,
          float* __restrict__ hvn1f)
{
    __shared__ __align__(16) u16 Xs[K_*XAP];     // X tile; later aliased as Y2
    __shared__ __align__(16) u16 Y1s[K_*YPAD];
    __shared__ float dhs[H_];
    __shared__ float matt[K_];
    __shared__ int   idxs[K_];
    __shared__ float stats[3];                   // mean, rstd, summask

    const int bn  = blockIdx.x;
    const int b   = bn >> 10;
    const int tid = threadIdx.x;
    const int lane = tid & 63, w = tid >> 6;     // w = 0..7

    const int fHV = flags[0], fHE = flags[1], fMA = flags[4];
    const int fb2 = flags[8], fb3 = flags[10];
    const int fg1 = flags[21], fbe1 = flags[22];

    if (tid < K_) { idxs[tid] = idxn[bn*K_ + tid]; matt[tid] = ldf(maskAtt, (size_t)bn*K_ + tid, fMA); }
    __syncthreads();
    if (tid == 0) { float s=0.f; for (int k=0;k<K_;k++) s += matt[k]; stats[2] = s; }

    for (int u = tid; u < 768; u += 512) {
        const int row = u >> 4, c8 = (u & 15) << 3;
        cp8(&Xs[row*XAP + c8],      hE, ((size_t)bn*K_ + row)*H_ + c8, fHE);
        cp8(&Xs[row*XAP + H_ + c8], hV, ((size_t)b*N_ + idxs[row])*H_ + c8, fHV);
    }
    __syncthreads();

    const int l15 = lane & 15, q = lane >> 4;
    const int n0 = w*16;                          // this wave's 16 output cols

    // ---- GEMM1: C-init from gv1 (center term + b1, precomputed) ----
    {
        f32x4 acc[3];
        const float g = gv1f[(size_t)bn*H_ + n0 + l15];
        for (int mt=0; mt<3; mt++) for (int r=0; r<4; r++) acc[mt][r] = g;
        mfma3w<256, XAP, CAT_, H_>(Xs, w1t, lane, n0, acc);   // W1 rows 128..383
        epi_gelu1<false>(acc, nullptr, 0, Y1s, lane, n0);
    }
    __syncthreads();

    u16* Y2s = Xs;
    {
        f32x4 acc[3] = {fzero(), fzero(), fzero()};
        mfma3w<H_, YPAD, H_, 0>(Y1s, w2t, lane, n0, acc);
        epi_gelu1<true>(acc, b2, fb2, Y2s, lane, n0);
    }
    __syncthreads();

    {
        f32x4 acc[3] = {fzero(), fzero(), fzero()};
        mfma3w<H_, YPAD, H_, 0>(Y2s, w3t, lane, n0, acc);
        float s0 = 0.f;
        for (int mt=0; mt<3; mt++)
            for (int r=0; r<4; r++)
                s0 += acc[mt][r]*matt[mt*16 + q*4 + r];
        s0 += __shfl_xor(s0,16); s0 += __shfl_xor(s0,32);
        if (q == 0) {
            const int col = n0 + l15;
            dhs[col] = (s0 + ldf(b3, col, fb3)*stats[2]) * INV_SCALE;
        }
    }
    __syncthreads();

    // ---- LN1 -> hvn1f (fp32 ws; ffn_fused consumes) ----
    if (w == 0) {
        float a = ldf(hV, (size_t)bn*H_ + lane,      fHV) + dhs[lane];
        float c = ldf(hV, (size_t)bn*H_ + lane + 64, fHV) + dhs[lane+64];
        float s = a + c, ss = a*a + c*c;
        for (int off=32; off>0; off>>=1) { s += __shfl_xor(s,off); ss += __shfl_xor(ss,off); }
        if (lane == 0) { float m = s*(1.f/H_); stats[0]=m; stats[1]=rsqrtf(ss*(1.f/H_)-m*m+EPS_); }
    }
    __syncthreads();
    if (tid < H_) {
        float h = ldf(hV, (size_t)bn*H_ + tid, fHV) + dhs[tid];
        hvn1f[(size_t)bn*H_ + tid] = (h - stats[0])*stats[1]*ldf(g1,tid,fg1) + ldf(be1,tid,fbe1);
    }
}

// ================= ffn_fused: FFN + LN2 + mask + gv11, 16 rows/block =================
__global__ void __launch_bounds__(256, 2)
ffn_fused(const float* __restrict__ hvn1f, const void* __restrict__ maskV,
          const u16* __restrict__ wintt, const void* __restrict__ bin,
          const u16* __restrict__ woutt, const void* __restrict__ bout,
          const u16* __restrict__ w11t, const void* __restrict__ b11,
          const void* __restrict__ g2, const void* __restrict__ be2,
          const int* __restrict__ flags,
          float* __restrict__ outV, u16* __restrict__ wsVn, float* __restrict__ gv11f)
{
    __shared__ __align__(16) float hvf[16*H_];     // fp32 hvn1 (residual)
    __shared__ __align__(16) u16   Xh[16*YPAD];    // bf16 A-tile of hvn1
    __shared__ __align__(16) u16   hid[16*HIDP];   // bf16 hidden 16x512
    __shared__ __align__(16) float h2f[16*MPAD];   // fp32 pre-LN2
    __shared__ __align__(16) u16   h2b[16*YPAD];   // bf16 LN2 out (gv11 A-tile)

    const int r0  = blockIdx.x*16;
    const int tid = threadIdx.x, lane = tid & 63, w = tid >> 6;
    const int l15 = lane & 15, q = lane >> 4;
    const int fMV = flags[3], fbin = flags[18], fbout = flags[20];
    const int fb11 = flags[12], fg2 = flags[23], fbe2 = flags[24];

    {   // stage hvn1 rows (fp32 + bf16)
        const int row = tid >> 4, c8 = (tid & 15) << 3;
        const float4* s = (const float4*)&hvn1f[(size_t)(r0+row)*H_ + c8];
        float4 a = s[0], b = s[1];
        *(float4*)&hvf[row*H_ + c8]     = a;
        *(float4*)&hvf[row*H_ + c8 + 4] = b;
        uint4 o; o.x = pk2(a.x,a.y); o.y = pk2(a.z,a.w); o.z = pk2(b.x,b.y); o.w = pk2(b.z,b.w);
        *(uint4*)&Xh[row*YPAD + c8] = o;
    }
    __syncthreads();

    // ---- GEMM1: hid[16x512]; wave w owns cols w*128..+127 (8 ct blocks) ----
    {
        f32x4 acc[8];
#pragma unroll
        for (int ct = 0; ct < 8; ct++) {
            const float bv = ldf(bin, w*128 + ct*16 + l15, fbin);
            for (int r=0;r<4;r++) acc[ct][r] = bv;
        }
#pragma unroll 1
        for (int k0 = 0; k0 < H_; k0 += 32) {
            const int ko = k0 + q*8;
            bf16x8 a = *(const bf16x8*)&Xh[l15*YPAD + ko];
#pragma unroll
            for (int ct = 0; ct < 8; ct++) {
                bf16x8 b = *(const bf16x8*)&wintt[(size_t)(w*128 + ct*16 + l15)*H_ + ko];
                acc[ct] = __builtin_amdgcn_mfma_f32_16x16x32_bf16(a,b,acc[ct],0,0,0);
            }
        }
#pragma unroll
        for (int ct = 0; ct < 8; ct++) {
            const int col = w*128 + ct*16 + l15;
            for (int r=0;r<4;r++)
                hid[(q*4 + r)*HIDP + col] = f2bf(gelu_ex(acc[ct][r]));
        }
    }
    __syncthreads();

    // ---- GEMM2: out 16x128; wave w owns 32 cols; + bout + fp32 residual ----
    {
        const int n0 = w*32;
        f32x4 c0 = fzero(), c1 = fzero();
#pragma unroll 1
        for (int k0 = 0; k0 < FF_; k0 += 32) {
            const int ko = k0 + q*8;
            bf16x8 a  = *(const bf16x8*)&hid[l15*HIDP + ko];
            bf16x8 b0 = *(const bf16x8*)&woutt[(size_t)(n0 + l15)*FF_ + ko];
            bf16x8 b1 = *(const bf16x8*)&woutt[(size_t)(n0 + 16 + l15)*FF_ + ko];
            c0 = __builtin_amdgcn_mfma_f32_16x16x32_bf16(a,b0,c0,0,0,0);
            c1 = __builtin_amdgcn_mfma_f32_16x16x32_bf16(a,b1,c1,0,0,0);
        }
        const float bo0 = ldf(bout, n0+l15, fbout), bo1 = ldf(bout, n0+16+l15, fbout);
        for (int r=0;r<4;r++) {
            const int row = q*4 + r;
            h2f[row*MPAD + n0+l15]    = c0[r] + bo0 + hvf[row*H_ + n0+l15];
            h2f[row*MPAD + n0+16+l15] = c1[r] + bo1 + hvf[row*H_ + n0+16+l15];
        }
    }
    __syncthreads();

    // ---- LN2 + mask; rows w, w+4, w+8, w+12 per wave ----
    for (int row = w; row < 16; row += 4) {
        float v0 = h2f[row*MPAD + lane], v1 = h2f[row*MPAD + lane + 64];
        float s = v0+v1, ss = v0*v0+v1*v1;
        for (int off=32; off>0; off>>=1) { s += __shfl_xor(s,off); ss += __shfl_xor(ss,off); }
        const float m = s*(1.f/H_);
        const float rstd = rsqrtf(ss*(1.f/H_) - m*m + EPS_);
        const float mk = ldf(maskV, r0+row, fMV);
        const float o0 = ((v0-m)*rstd*ldf(g2,lane,fg2)    + ldf(be2,lane,fbe2))    * mk;
        const float o1 = ((v1-m)*rstd*ldf(g2,lane+64,fg2) + ldf(be2,lane+64,fbe2)) * mk;
        outV[(size_t)(r0+row)*H_ + lane]      = o0;
        outV[(size_t)(r0+row)*H_ + lane + 64] = o1;
        const u16 u0 = f2bf(o0), u1 = f2bf(o1);
        wsVn[(size_t)(r0+row)*H_ + lane]      = u0;
        wsVn[(size_t)(r0+row)*H_ + lane + 64] = u1;
        h2b[row*YPAD + lane]      = u0;
        h2b[row*YPAD + lane + 64] = u1;
    }
    __syncthreads();

    // ---- GEMM3: gv11 = h2b @ W11[0:128,:] + b11 (edge center term) ----
    {
        const int n0 = w*32;
        f32x4 d0, d1;
        { float b0v = ldf(b11, n0+l15, fb11), b1v = ldf(b11, n0+16+l15, fb11);
          for (int r=0;r<4;r++){ d0[r]=b0v; d1[r]=b1v; } }
#pragma unroll 1
        for (int k0 = 0; k0 < H_; k0 += 32) {
            const int ko = k0 + q*8;
            bf16x8 a  = *(const bf16x8*)&h2b[l15*YPAD + ko];
            bf16x8 b0 = *(const bf16x8*)&w11t[(size_t)(n0 + l15)*CAT_ + ko];
            bf16x8 b1 = *(const bf16x8*)&w11t[(size_t)(n0 + 16 + l15)*CAT_ + ko];
            d0 = __builtin_amdgcn_mfma_f32_16x16x32_bf16(a,b0,d0,0,0,0);
            d1 = __builtin_amdgcn_mfma_f32_16x16x32_bf16(a,b1,d1,0,0,0);
        }
        for (int r=0;r<4;r++) {
            gv11f[(size_t)(r0 + q*4 + r)*H_ + n0 + l15]      = d0[r];
            gv11f[(size_t)(r0 + q*4 + r)*H_ + n0 + 16 + l15] = d1[r];
        }
    }
}

// ================= edge kernel: MFMA; 512 threads, 8 waves =================
// R13: one 16-col block per wave. Wave w writes Ms tile (w&1) at in-tile col
// (w>>1)*16+l15 — byte-identical layout to R8's ct-split, so LN read side is
// unchanged. Even waves write Ms0 (Y1s, dead after GEMM2 barrier) right after
// their GEMM3; odd waves hold acc across one barrier (all Y2 reads done), then
// write Ms1 (hvnbs). Spill tripwire: WRITE_SIZE = 49,152 KB.
__global__ void __launch_bounds__(512, 8)
edge_mfma(const u16* __restrict__ wsVn, const void* __restrict__ hE, const int* __restrict__ idxn,
          const u16* __restrict__ w11t,
          const u16* __restrict__ w12t, const void* __restrict__ b12,
          const u16* __restrict__ w13t, const void* __restrict__ b13,
          const void* __restrict__ g3, const void* __restrict__ be3,
          const float* __restrict__ gv11f,
          const int* __restrict__ flags,
          float* __restrict__ outE)
{
    __shared__ __align__(16) u16 hEs[K_*YPAD];    // hE tile (bf16) — preserved through LN
    __shared__ __align__(16) u16 hvnbs[K_*YPAD];  // hv_nb tile; aliased as Y2, then Ms1
    __shared__ __align__(16) u16 Y1s[K_*YPAD];    // Y1 tile; aliased as Ms0
    __shared__ int idxs[K_];

    const int bn  = blockIdx.x;
    const int b   = bn >> 10;
    const int tid = threadIdx.x;
    const int lane = tid & 63, w = tid >> 6;      // w = 0..7

    const int fHE = flags[1];
    const int fb12 = flags[14], fb13 = flags[16];
    const int fg3 = flags[25], fbe3 = flags[26];

    if (tid < K_) idxs[tid] = idxn[bn*K_ + tid];
    __syncthreads();

    const u16* hVb = wsVn + (size_t)b*N_*H_;
    for (int u = tid; u < 768; u += 512) {
        const int row = u >> 4, c8 = (u & 15) << 3;
        cp8(&hEs[row*YPAD + c8], hE, ((size_t)bn*K_ + row)*H_ + c8, fHE);
        *(uint4*)&hvnbs[row*YPAD + c8] = *(const uint4*)&hVb[(size_t)idxs[row]*H_ + c8];
    }
    __syncthreads();

    const int l15 = lane & 15, q = lane >> 4;
    const int n0 = w*16;

    // GEMM1: C-init from gv11; two half-K passes over the split X tile.
    {
        f32x4 acc[3];
        const float g = gv11f[(size_t)bn*H_ + n0 + l15];
        for (int mt=0; mt<3; mt++) for (int r=0; r<4; r++) acc[mt][r] = g;
        mfma3w<H_, YPAD, CAT_, H_>(hEs,   w11t, lane, n0, acc);   // W11 rows 128..255
        mfma3w<H_, YPAD, CAT_, 2*H_>(hvnbs, w11t, lane, n0, acc); // W11 rows 256..383
        epi_gelu1<false>(acc, nullptr, 0, Y1s, lane, n0);
    }
    __syncthreads();

    u16* Y2s = hvnbs;                 // hv_nb dead after GEMM1
    {
        f32x4 acc[3] = {fzero(), fzero(), fzero()};
        mfma3w<H_, YPAD, H_, 0>(Y1s, w12t, lane, n0, acc);
        epi_gelu1<true>(acc, b12, fb12, Y2s, lane, n0);
    }
    __syncthreads();                  // Y2 visible; ALL Y1s reads done -> Y1s reusable

    // GEMM3: wave w -> Ms tile (w&1), in-tile col (w>>1)*16 + l15
    {
        f32x4 acc[3] = {fzero(), fzero(), fzero()};
        mfma3w<H_, YPAD, H_, 0>(Y2s, w13t, lane, n0, acc);
        const float bv = ldf(b13, n0 + l15, fb13);
        const int ci = (w >> 1)*16 + l15;
        if ((w & 1) == 0) {           // Ms0 = Y1s alias: safe now (Y1s dead)
            float* Ms0 = (float*)Y1s;
            for (int mt=0; mt<3; mt++)
                for (int r=0; r<4; r++)
                    Ms0[(mt*16 + q*4 + r)*MSP + ci] = acc[mt][r] + bv;
            __syncthreads();          // all Y2 (hvnbs) reads done
        } else {
            __syncthreads();          // all Y2 (hvnbs) reads done
            float* Ms1 = (float*)hvnbs;
            for (int mt=0; mt<3; mt++)
                for (int r=0; r<4; r++)
                    Ms1[(mt*16 + q*4 + r)*MSP + ci] = acc[mt][r] + bv;
        }
    }
    __syncthreads();                  // Ms0 + Ms1 visible

    // h_En = LN(h_E + M), one wave per row; hE from the PRESERVED LDS tile.
    {
        const float* Ms0c = (const float*)Y1s;
        const float* Ms1c = (const float*)hvnbs;
        const int g0  = lane >> 4;
        const int ci0 = (g0 >> 1)*16 + (lane & 15);   // in-tile col for c=lane
        const int ci1 = ci0 + 32;                     // in-tile col for c=lane+64
        const float* Mt = (g0 & 1) ? Ms1c : Ms0c;
        const float gg0 = ldf(g3, lane, fg3),   gg1 = ldf(g3, lane+64, fg3);
        const float bb0 = ldf(be3, lane, fbe3), bb1 = ldf(be3, lane+64, fbe3);
        for (int row = w; row < K_; row += 8) {
            const size_t e0 = ((size_t)bn*K_ + row)*H_;
            float v0 = bf2f(hEs[row*YPAD + lane])      + Mt[row*MSP + ci0];
            float v1 = bf2f(hEs[row*YPAD + lane + 64]) + Mt[row*MSP + ci1];
            float s = v0+v1, ss = v0*v0+v1*v1;
            for (int off=32; off>0; off>>=1) { s += __shfl_xor(s,off); ss += __shfl_xor(ss,off); }
            const float m = s*(1.f/H_);
            const float rstd = rsqrtf(ss*(1.f/H_) - m*m + EPS_);
            outE[e0 + lane]      = (v0-m)*rstd*gg0 + bb0;
            outE[e0 + lane + 64] = (v1-m)*rstd*gg1 + bb1;
        }
    }
}

extern "C" void kernel_launch(void* const* d_in, const int* in_sizes, int n_in,
                              void* d_out, int out_size, void* d_ws, size_t ws_size,
                              hipStream_t stream)
{
    const void* hV      = d_in[0];
    const void* hE      = d_in[1];
    const void* maskV   = d_in[3];
    const void* maskAtt = d_in[4];
    const void* W2b  = d_in[8];
    const void* W3b  = d_in[10];
    const void* W11b = d_in[12];
    const void* W12b = d_in[14];
    const void* W13b = d_in[16];
    const void* Winb = d_in[18];
    const void* Woutb= d_in[20];
    const void* ln1g = d_in[21]; const void* ln1b = d_in[22];
    const void* ln2g = d_in[23]; const void* ln2b = d_in[24];
    const void* ln3g = d_in[25]; const void* ln3b = d_in[26];

    // ws layout (u16 units) — mirrored inside mega_prep
    u16* ws    = (u16*)d_ws;
    u16* w1t   = ws;                        // 128*384
    u16* w2t   = w1t   + 128*384;           // 128*128
    u16* w3t   = w2t   + 128*128;
    u16* w11t  = w3t   + 128*128;           // 128*384
    u16* w12t  = w11t  + 128*384;
    u16* w13t  = w12t  + 128*128;
    u16* wintt = w13t  + 128*128;           // 512*128
    u16* woutt = wintt + 512*128;           // 128*512
    int* idxn  = (int*)(woutt + 128*512);   // 98304 int32
    u16* wsVn  = (u16*)(idxn + B_*N_*K_);   // 262144 bf16
    float* gv1f  = (float*)(wsVn + B_*N_*H_);   // 262144 f32
    float* hvn1f = gv1f  + (size_t)B_*N_*H_;    // 262144 f32
    float* gv11f = hvn1f + (size_t)B_*N_*H_;    // 262144 f32
    int* flags = (int*)(gv11f + (size_t)B_*N_*H_);  // 27 ints

    Ptrs27 P;
    for (int i = 0; i < 27; i++) { P.p[i] = d_in[i]; P.n[i] = in_sizes[i]; }

    // ONE prep launch: repacks 0..71 + prep_idx 72..455 + probes 456..482 + gv1 483..610
    hipLaunchKernelGGL(mega_prep, dim3(611), dim3(256), 0, stream, P, ws, flags, gv1f);

    float* outV = (float*)d_out;
    float* outE = outV + (size_t)B_*N_*H_;

    hipLaunchKernelGGL(node_mfma, dim3(B_*N_), dim3(512), 0, stream,
                       hV, hE, idxn, maskAtt,
                       w1t, w2t, W2b, w3t, W3b,
                       ln1g, ln1b, gv1f, flags, hvn1f);
    hipLaunchKernelGGL(ffn_fused, dim3(B_*N_/16), dim3(256), 0, stream,
                       hvn1f, maskV, wintt, Winb, woutt, Woutb,
                       w11t, W11b, ln2g, ln2b, flags, outV, wsVn, gv11f);
    hipLaunchKernelGGL(edge_mfma, dim3(B_*N_), dim3(512), 0, stream,
                       wsVn, hE, idxn,
                       w11t, w12t, W12b, w13t, W13b,
                       ln3g, ln3b, gv11f, flags, outE);
}

// Round 14
// 267.809 us; speedup vs baseline: 1.0366x; 1.0110x over previous
//
#include <hip/hip_runtime.h>
#include <cstdint>
#include <cstddef>

typedef unsigned short u16;
typedef unsigned int   u32;
typedef __bf16  bf16x8 __attribute__((ext_vector_type(8)));
typedef float   f32x4  __attribute__((ext_vector_type(4)));

#define B_    2
#define N_    1024
#define K_    48
#define H_    128
#define CAT_  384
#define FF_   512
#define YPAD  136   // bf16 row pitch for 128-col tiles (128+8)
#define HIDP  520   // bf16 row pitch for ffn hid tile (512+8)
#define MPAD  132   // fp32 row pitch for 128-col fp32 tiles
#define MSP   68    // fp32 row pitch for 64-col M half-tiles (edge)
#define XAP   264   // node X-tile pitch (256+8)
#define EPS_  1e-5f
#define INV_SCALE (1.0f/48.0f)

__device__ __forceinline__ float bf2f(u16 u){ u32 x=((u32)u)<<16; float f; __builtin_memcpy(&f,&x,4); return f; }
__device__ __forceinline__ u16 f2bf(float f){ u32 x; __builtin_memcpy(&x,&f,4); x=(x+0x7FFFu+((x>>16)&1u))>>16; return (u16)x; }
__device__ __forceinline__ u32 pk2(float lo, float hi){ return (u32)f2bf(lo) | ((u32)f2bf(hi)<<16); }

// Branch-free exact-GELU: erf via Abramowitz-Stegun 7.1.26 (|err|<=1.5e-7).
__device__ __forceinline__ float gelu_ex(float x){
    const float s = x * 0.7071067811865476f;
    const float a = fabsf(s);
    const float t = __builtin_amdgcn_rcpf(__builtin_fmaf(0.3275911f, a, 1.0f));
    float p = __builtin_fmaf(1.061405429f, t, -1.453152027f);
    p = __builtin_fmaf(p, t,  1.421413741f);
    p = __builtin_fmaf(p, t, -0.284496736f);
    p = __builtin_fmaf(p, t,  0.254829592f);
    p *= t;
    const float e = __expf(-s*s);
    const float erfa = __builtin_fmaf(-p, e, 1.0f);
    const float erf  = __builtin_copysignf(erfa, s);
    return 0.5f*x*(1.0f+erf);
}
__device__ __forceinline__ f32x4 fzero(){ f32x4 v; v[0]=0.f; v[1]=0.f; v[2]=0.f; v[3]=0.f; return v; }

__device__ __forceinline__ float ldf(const void* p, size_t i, int bf){
    return bf ? bf2f(((const u16*)p)[i]) : ((const float*)p)[i];
}
// 8 consecutive elems -> bf16 LDS (dtype-aware)
__device__ __forceinline__ void cp8(u16* dst, const void* src, size_t eoff, int bf){
    if (bf) { *(uint4*)dst = *(const uint4*)((const u16*)src + eoff); }
    else {
        const float4* s = (const float4*)((const float*)src + eoff);
        float4 a = s[0], b = s[1];
        uint4 o; o.x = pk2(a.x,a.y); o.y = pk2(a.z,a.w); o.z = pk2(b.x,b.y); o.w = pk2(b.z,b.w);
        *(uint4*)dst = o;
    }
}

// ---------------- dtype probes ----------------
__device__ int probe_f_d(const void* p, int n_elems){
    const u32 w0 = ((const u32*)p)[0];
    if (w0 == 0x3F803F80u) return 1;
    if (w0 == 0x3F800000u) return 0;
    const u16* s = (const u16*)p;
    int m = n_elems < 128 ? n_elems : 128;
    for (int j = 0; j < m; j++) { float v = fabsf(bf2f(s[j])); if (v > 1e6f) return 0; }
    return 1;
}
__device__ int probe_i_d(const int* p){
    const u32* s = (const u32*)p;
    for (int j = 0; j < 128; j++) if (s[2*j+1] != 0u) return 0;
    return 1;
}
struct Ptrs27 { const void* p[27]; int n[27]; };

// ================= mega_prep: all repacks + idx + probes in ONE launch =================
// 64x64 LDS-tiled transpose: coalesced reads AND writes (R9). Block map:
// repack 0..71, prep_idx 72..455, probes 456..482.
__global__ void __launch_bounds__(256)
mega_prep(Ptrs27 P, u16* __restrict__ ws, int* __restrict__ flags)
{
    // ws layout (u16 units) — must match kernel_launch
    u16* w1t   = ws;
    u16* w2t   = w1t   + 128*384;
    u16* w3t   = w2t   + 128*128;
    u16* w11t  = w3t   + 128*128;
    u16* w12t  = w11t  + 128*384;
    u16* w13t  = w12t  + 128*128;
    u16* wintt = w13t  + 128*128;
    u16* woutt = wintt + 512*128;
    int* idxn  = (int*)(woutt + 128*512);

    __shared__ int sbf;
    __shared__ __align__(16) u16 tile[64][65];   // 65-pitch: 2-way max aliasing (free)
    const int blk = blockIdx.x;
    const int tid = threadIdx.x;

    if (blk >= 456) {                  // ---- probe job: 27 blocks ----
        const int t = blk - 456;
        if (tid == 0)
            flags[t] = (t == 2) ? probe_i_d((const int*)P.p[t]) : probe_f_d(P.p[t], P.n[t]);
        return;
    }
    if (blk >= 72) {                   // ---- prep_idx: 384 blocks ----
        const int* s = (const int*)P.p[2];
        if (tid == 0) sbf = probe_i_d(s);
        __syncthreads();
        const int w64 = sbf;
        const int i = (blk - 72)*256 + tid;
        if (i < B_*N_*K_) idxn[i] = w64 ? s[2*i] : s[i];
        return;
    }
    // ---- weight repack: [ri][co] -> bf16 [co][ri], one 64x64 tile per block ----
    const void* src; u16* dst; int ri, co, rel;
    if      (blk < 12) { src=P.p[5];  dst=w1t;   ri=384; co=128; rel=blk;     }
    else if (blk < 16) { src=P.p[7];  dst=w2t;   ri=128; co=128; rel=blk-12;  }
    else if (blk < 20) { src=P.p[9];  dst=w3t;   ri=128; co=128; rel=blk-16;  }
    else if (blk < 32) { src=P.p[11]; dst=w11t;  ri=384; co=128; rel=blk-20;  }
    else if (blk < 36) { src=P.p[13]; dst=w12t;  ri=128; co=128; rel=blk-32;  }
    else if (blk < 40) { src=P.p[15]; dst=w13t;  ri=128; co=128; rel=blk-36;  }
    else if (blk < 56) { src=P.p[17]; dst=wintt; ri=128; co=512; rel=blk-40;  }
    else               { src=P.p[19]; dst=woutt; ri=512; co=128; rel=blk-56;  }
    if (tid == 0) sbf = probe_f_d(src, 128);
    __syncthreads();
    const int bf = sbf;
    const int tc = co >> 6;
    const int r0 = (rel / tc) * 64, o0 = (rel % tc) * 64;
    const int lr = tid >> 6, lc = tid & 63;
#pragma unroll
    for (int pph = 0; pph < 16; pph++) {
        const int row = pph*4 + lr;
        tile[row][lc] = bf ? ((const u16*)src)[(size_t)(r0+row)*co + o0 + lc]
                           : f2bf(((const float*)src)[(size_t)(r0+row)*co + o0 + lc]);
    }
    __syncthreads();
#pragma unroll
    for (int pph = 0; pph < 16; pph++) {
        const int o = pph*4 + lr;
        dst[(size_t)(o0+o)*ri + r0 + lc] = tile[lc][o];   // contiguous u16 over lc
    }
}

// ---- single-column-block GEMM pass (register-pressure-reduced) ----
// acc must be statically indexed at call sites (rule #20; R4 post-mortem).
// k-loop unroll BOUNDED at 2 (R10/R11): full unroll hoisted up to 8 iters x 16
// fragment VGPRs over the (256,4) 128-reg cap -> ~26 MB/dispatch scratch spill.
template<int KD, int AP, int LD, int KOFF>
__device__ __forceinline__ void mfma3x1(const u16* As, const u16* __restrict__ wt, int tid, int ct, f32x4 acc[3])
{
    const int lane = tid & 63;
    const int l15  = lane & 15, q = lane >> 4;
    const int n0   = (tid >> 6) * 32 + ct*16;
#pragma unroll 2
    for (int k0 = 0; k0 < KD; k0 += 32) {
        const int ko = k0 + q*8;
        bf16x8 b0 = *(const bf16x8*)&wt[(size_t)(n0 + l15)*LD + KOFF + ko];
        bf16x8 a0 = *(const bf16x8*)&As[(l15     )*AP + ko];
        bf16x8 a1 = *(const bf16x8*)&As[(l15 + 16)*AP + ko];
        bf16x8 a2 = *(const bf16x8*)&As[(l15 + 32)*AP + ko];
        acc[0] = __builtin_amdgcn_mfma_f32_16x16x32_bf16(a0,b0,acc[0],0,0,0);
        acc[1] = __builtin_amdgcn_mfma_f32_16x16x32_bf16(a1,b0,acc[1],0,0,0);
        acc[2] = __builtin_amdgcn_mfma_f32_16x16x32_bf16(a2,b0,acc[2],0,0,0);
    }
}
// D[row=mt*16+(lane>>4)*4+r][col=(wave*32)+ct*16+(lane&15)]  (m89-verified C/D mapping)
template<bool BIAS>
__device__ __forceinline__ void epi_gelu1(const f32x4 acc[3], const void* __restrict__ bias, int bf,
                                          u16* Outs, int tid, int ct)
{
    const int lane = tid & 63, l15 = lane & 15, q = lane >> 4;
    const int col = (tid>>6)*32 + ct*16 + l15;
    float bv = 0.f;
    if constexpr (BIAS) bv = ldf(bias, col, bf);
    for (int mt = 0; mt < 3; mt++)
        for (int r = 0; r < 4; r++)
            Outs[(mt*16 + q*4 + r)*YPAD + col] = f2bf(gelu_ex(acc[mt][r] + bv));
}

// ================= pre_gv1: gv1 = bf16(hV) @ W1[0:128,:] + b1, all 2048 rows =================
__global__ void __launch_bounds__(256, 2)
pre_gv1(const void* __restrict__ hV, const u16* __restrict__ w1t, const void* __restrict__ b1,
        const int* __restrict__ flags, float* __restrict__ gv1f)
{
    __shared__ __align__(16) u16 Ah[16*YPAD];
    const int r0 = blockIdx.x*16;
    const int tid = threadIdx.x, lane = tid & 63, w = tid >> 6;
    const int l15 = lane & 15, q = lane >> 4;
    const int fHV = flags[0], fb1 = flags[6];

    { const int row = tid >> 4, c8 = (tid & 15) << 3;
      cp8(&Ah[row*YPAD + c8], hV, (size_t)(r0+row)*H_ + c8, fHV); }
    __syncthreads();

    const int n0 = w*32;
    f32x4 a0, a1;
    { float b0v = ldf(b1, n0+l15, fb1), b1v = ldf(b1, n0+16+l15, fb1);
      for (int r=0;r<4;r++){ a0[r]=b0v; a1[r]=b1v; } }
#pragma unroll 1
    for (int k0 = 0; k0 < H_; k0 += 32) {
        const int ko = k0 + q*8;
        bf16x8 a  = *(const bf16x8*)&Ah[l15*YPAD + ko];
        bf16x8 b0 = *(const bf16x8*)&w1t[(size_t)(n0 + l15)*CAT_ + ko];
        bf16x8 b1 = *(const bf16x8*)&w1t[(size_t)(n0 + 16 + l15)*CAT_ + ko];
        a0 = __builtin_amdgcn_mfma_f32_16x16x32_bf16(a,b0,a0,0,0,0);
        a1 = __builtin_amdgcn_mfma_f32_16x16x32_bf16(a,b1,a1,0,0,0);
    }
    for (int r=0;r<4;r++) {
        gv1f[(size_t)(r0 + q*4 + r)*H_ + n0 + l15]      = a0[r];
        gv1f[(size_t)(r0 + q*4 + r)*H_ + n0 + 16 + l15] = a1[r];
    }
}

// ================= node kernel: message + LN1 only =================
__global__ void __launch_bounds__(256, 4)
node_mfma(const void* __restrict__ hV, const void* __restrict__ hE, const int* __restrict__ idxn,
          const void* __restrict__ maskAtt,
          const u16* __restrict__ w1t,
          const u16* __restrict__ w2t, const void* __restrict__ b2,
          const u16* __restrict__ w3t, const void* __restrict__ b3,
          const void* __restrict__ g1, const void* __restrict__ be1,
          const float* __restrict__ gv1f,
          const int* __restrict__ flags,
          float* __restrict__ hvn1f)
{
    __shared__ __align__(16) u16 Xs[K_*XAP];     // X tile; later aliased as Y2
    __shared__ __align__(16) u16 Y1s[K_*YPAD];
    __shared__ float dhs[H_];
    __shared__ float matt[K_];
    __shared__ int   idxs[K_];
    __shared__ float stats[3];                   // mean, rstd, summask

    const int bn  = blockIdx.x;
    const int b   = bn >> 10;
    const int tid = threadIdx.x;
    const int lane = tid & 63, w = tid >> 6;

    const int fHV = flags[0], fHE = flags[1], fMA = flags[4];
    const int fb2 = flags[8], fb3 = flags[10];
    const int fg1 = flags[21], fbe1 = flags[22];

    if (tid < K_) { idxs[tid] = idxn[bn*K_ + tid]; matt[tid] = ldf(maskAtt, (size_t)bn*K_ + tid, fMA); }
    __syncthreads();
    if (tid == 0) { float s=0.f; for (int k=0;k<K_;k++) s += matt[k]; stats[2] = s; }

    for (int u = tid; u < 768; u += 256) {
        const int row = u >> 4, c8 = (u & 15) << 3;
        cp8(&Xs[row*XAP + c8],      hE, ((size_t)bn*K_ + row)*H_ + c8, fHE);
        cp8(&Xs[row*XAP + H_ + c8], hV, ((size_t)b*N_ + idxs[row])*H_ + c8, fHV);
    }
    __syncthreads();

    const int l15 = lane & 15, q = lane >> 4, n0 = w*32;

    // ---- GEMM1: C-init from gv1 (center term + b1, precomputed) ----
#pragma unroll 1
    for (int ct = 0; ct < 2; ct++) {
        f32x4 acc[3];
        const float g = gv1f[(size_t)bn*H_ + n0 + ct*16 + l15];
        for (int mt=0; mt<3; mt++) for (int r=0; r<4; r++) acc[mt][r] = g;
        mfma3x1<256, XAP, CAT_, H_>(Xs, w1t, tid, ct, acc);   // W1 rows 128..383
        epi_gelu1<false>(acc, nullptr, 0, Y1s, tid, ct);
    }
    __syncthreads();

    u16* Y2s = Xs;
#pragma unroll 1
    for (int ct = 0; ct < 2; ct++) {
        f32x4 acc[3] = {fzero(), fzero(), fzero()};
        mfma3x1<H_, YPAD, H_, 0>(Y1s, w2t, tid, ct, acc);
        epi_gelu1<true>(acc, b2, fb2, Y2s, tid, ct);
    }
    __syncthreads();

#pragma unroll 1
    for (int ct = 0; ct < 2; ct++) {
        f32x4 acc[3] = {fzero(), fzero(), fzero()};
        mfma3x1<H_, YPAD, H_, 0>(Y2s, w3t, tid, ct, acc);
        float s0 = 0.f;
        for (int mt=0; mt<3; mt++)
            for (int r=0; r<4; r++)
                s0 += acc[mt][r]*matt[mt*16 + q*4 + r];
        s0 += __shfl_xor(s0,16); s0 += __shfl_xor(s0,32);
        if (q == 0) {
            const int col = n0 + ct*16 + l15;
            dhs[col] = (s0 + ldf(b3, col, fb3)*stats[2]) * INV_SCALE;
        }
    }
    __syncthreads();

    // ---- LN1 -> hvn1f (fp32 ws; ffn_fused consumes) ----
    if (w == 0) {
        float a = ldf(hV, (size_t)bn*H_ + lane,      fHV) + dhs[lane];
        float c = ldf(hV, (size_t)bn*H_ + lane + 64, fHV) + dhs[lane+64];
        float s = a + c, ss = a*a + c*c;
        for (int off=32; off>0; off>>=1) { s += __shfl_xor(s,off); ss += __shfl_xor(ss,off); }
        if (lane == 0) { float m = s*(1.f/H_); stats[0]=m; stats[1]=rsqrtf(ss*(1.f/H_)-m*m+EPS_); }
    }
    __syncthreads();
    if (tid < H_) {
        float h = ldf(hV, (size_t)bn*H_ + tid, fHV) + dhs[tid];
        hvn1f[(size_t)bn*H_ + tid] = (h - stats[0])*stats[1]*ldf(g1,tid,fg1) + ldf(be1,tid,fbe1);
    }
}

// ================= ffn_fused: FFN + LN2 + mask + gv11, 16 rows/block =================
__global__ void __launch_bounds__(256, 2)
ffn_fused(const float* __restrict__ hvn1f, const void* __restrict__ maskV,
          const u16* __restrict__ wintt, const void* __restrict__ bin,
          const u16* __restrict__ woutt, const void* __restrict__ bout,
          const u16* __restrict__ w11t, const void* __restrict__ b11,
          const void* __restrict__ g2, const void* __restrict__ be2,
          const int* __restrict__ flags,
          float* __restrict__ outV, u16* __restrict__ wsVn, float* __restrict__ gv11f)
{
    __shared__ __align__(16) float hvf[16*H_];     // fp32 hvn1 (residual)
    __shared__ __align__(16) u16   Xh[16*YPAD];    // bf16 A-tile of hvn1
    __shared__ __align__(16) u16   hid[16*HIDP];   // bf16 hidden 16x512
    __shared__ __align__(16) float h2f[16*MPAD];   // fp32 pre-LN2
    __shared__ __align__(16) u16   h2b[16*YPAD];   // bf16 LN2 out (gv11 A-tile)

    const int r0  = blockIdx.x*16;
    const int tid = threadIdx.x, lane = tid & 63, w = tid >> 6;
    const int l15 = lane & 15, q = lane >> 4;
    const int fMV = flags[3], fbin = flags[18], fbout = flags[20];
    const int fb11 = flags[12], fg2 = flags[23], fbe2 = flags[24];

    {   // stage hvn1 rows (fp32 + bf16)
        const int row = tid >> 4, c8 = (tid & 15) << 3;
        const float4* s = (const float4*)&hvn1f[(size_t)(r0+row)*H_ + c8];
        float4 a = s[0], b = s[1];
        *(float4*)&hvf[row*H_ + c8]     = a;
        *(float4*)&hvf[row*H_ + c8 + 4] = b;
        uint4 o; o.x = pk2(a.x,a.y); o.y = pk2(a.z,a.w); o.z = pk2(b.x,b.y); o.w = pk2(b.z,b.w);
        *(uint4*)&Xh[row*YPAD + c8] = o;
    }
    __syncthreads();

    // ---- GEMM1: hid[16x512]; wave w owns cols w*128..+127 (8 ct blocks) ----
    {
        f32x4 acc[8];
#pragma unroll
        for (int ct = 0; ct < 8; ct++) {
            const float bv = ldf(bin, w*128 + ct*16 + l15, fbin);
            for (int r=0;r<4;r++) acc[ct][r] = bv;
        }
#pragma unroll 1
        for (int k0 = 0; k0 < H_; k0 += 32) {
            const int ko = k0 + q*8;
            bf16x8 a = *(const bf16x8*)&Xh[l15*YPAD + ko];
#pragma unroll
            for (int ct = 0; ct < 8; ct++) {
                bf16x8 b = *(const bf16x8*)&wintt[(size_t)(w*128 + ct*16 + l15)*H_ + ko];
                acc[ct] = __builtin_amdgcn_mfma_f32_16x16x32_bf16(a,b,acc[ct],0,0,0);
            }
        }
#pragma unroll
        for (int ct = 0; ct < 8; ct++) {
            const int col = w*128 + ct*16 + l15;
            for (int r=0;r<4;r++)
                hid[(q*4 + r)*HIDP + col] = f2bf(gelu_ex(acc[ct][r]));
        }
    }
    __syncthreads();

    // ---- GEMM2: out 16x128; wave w owns 32 cols; + bout + fp32 residual ----
    {
        const int n0 = w*32;
        f32x4 c0 = fzero(), c1 = fzero();
#pragma unroll 1
        for (int k0 = 0; k0 < FF_; k0 += 32) {
            const int ko = k0 + q*8;
            bf16x8 a  = *(const bf16x8*)&hid[l15*HIDP + ko];
            bf16x8 b0 = *(const bf16x8*)&woutt[(size_t)(n0 + l15)*FF_ + ko];
            bf16x8 b1 = *(const bf16x8*)&woutt[(size_t)(n0 + 16 + l15)*FF_ + ko];
            c0 = __builtin_amdgcn_mfma_f32_16x16x32_bf16(a,b0,c0,0,0,0);
            c1 = __builtin_amdgcn_mfma_f32_16x16x32_bf16(a,b1,c1,0,0,0);
        }
        const float bo0 = ldf(bout, n0+l15, fbout), bo1 = ldf(bout, n0+16+l15, fbout);
        for (int r=0;r<4;r++) {
            const int row = q*4 + r;
            h2f[row*MPAD + n0+l15]    = c0[r] + bo0 + hvf[row*H_ + n0+l15];
            h2f[row*MPAD + n0+16+l15] = c1[r] + bo1 + hvf[row*H_ + n0+16+l15];
        }
    }
    __syncthreads();

    // ---- LN2 + mask; rows w, w+4, w+8, w+12 per wave ----
    for (int row = w; row < 16; row += 4) {
        float v0 = h2f[row*MPAD + lane], v1 = h2f[row*MPAD + lane + 64];
        float s = v0+v1, ss = v0*v0+v1*v1;
        for (int off=32; off>0; off>>=1) { s += __shfl_xor(s,off); ss += __shfl_xor(ss,off); }
        const float m = s*(1.f/H_);
        const float rstd = rsqrtf(ss*(1.f/H_) - m*m + EPS_);
        const float mk = ldf(maskV, r0+row, fMV);
        const float o0 = ((v0-m)*rstd*ldf(g2,lane,fg2)    + ldf(be2,lane,fbe2))    * mk;
        const float o1 = ((v1-m)*rstd*ldf(g2,lane+64,fg2) + ldf(be2,lane+64,fbe2)) * mk;
        outV[(size_t)(r0+row)*H_ + lane]      = o0;
        outV[(size_t)(r0+row)*H_ + lane + 64] = o1;
        const u16 u0 = f2bf(o0), u1 = f2bf(o1);
        wsVn[(size_t)(r0+row)*H_ + lane]      = u0;
        wsVn[(size_t)(r0+row)*H_ + lane + 64] = u1;
        h2b[row*YPAD + lane]      = u0;
        h2b[row*YPAD + lane + 64] = u1;
    }
    __syncthreads();

    // ---- GEMM3: gv11 = h2b @ W11[0:128,:] + b11 (edge center term) ----
    {
        const int n0 = w*32;
        f32x4 d0, d1;
        { float b0v = ldf(b11, n0+l15, fb11), b1v = ldf(b11, n0+16+l15, fb11);
          for (int r=0;r<4;r++){ d0[r]=b0v; d1[r]=b1v; } }
#pragma unroll 1
        for (int k0 = 0; k0 < H_; k0 += 32) {
            const int ko = k0 + q*8;
            bf16x8 a  = *(const bf16x8*)&h2b[l15*YPAD + ko];
            bf16x8 b0 = *(const bf16x8*)&w11t[(size_t)(n0 + l15)*CAT_ + ko];
            bf16x8 b1 = *(const bf16x8*)&w11t[(size_t)(n0 + 16 + l15)*CAT_ + ko];
            d0 = __builtin_amdgcn_mfma_f32_16x16x32_bf16(a,b0,d0,0,0,0);
            d1 = __builtin_amdgcn_mfma_f32_16x16x32_bf16(a,b1,d1,0,0,0);
        }
        for (int r=0;r<4;r++) {
            gv11f[(size_t)(r0 + q*4 + r)*H_ + n0 + l15]      = d0[r];
            gv11f[(size_t)(r0 + q*4 + r)*H_ + n0 + 16 + l15] = d1[r];
        }
    }
}

// ================= edge kernel: MFMA =================
// (256,4) + Ms half-tile split (R8) + preserved hEs tile (R10) + bounded
// mfma3x1 unroll (R11, spill fix). Best-measured configuration of the session.
__global__ void __launch_bounds__(256, 4)
edge_mfma(const u16* __restrict__ wsVn, const void* __restrict__ hE, const int* __restrict__ idxn,
          const u16* __restrict__ w11t,
          const u16* __restrict__ w12t, const void* __restrict__ b12,
          const u16* __restrict__ w13t, const void* __restrict__ b13,
          const void* __restrict__ g3, const void* __restrict__ be3,
          const float* __restrict__ gv11f,
          const int* __restrict__ flags,
          float* __restrict__ outE)
{
    __shared__ __align__(16) u16 hEs[K_*YPAD];    // hE tile (bf16) — preserved through LN
    __shared__ __align__(16) u16 hvnbs[K_*YPAD];  // hv_nb tile; aliased as Y2, then Ms1
    __shared__ __align__(16) u16 Y1s[K_*YPAD];    // Y1 tile; aliased as Ms0
    __shared__ int idxs[K_];

    const int bn  = blockIdx.x;
    const int b   = bn >> 10;
    const int tid = threadIdx.x;
    const int lane = tid & 63, w = tid >> 6;

    const int fHE = flags[1];
    const int fb12 = flags[14], fb13 = flags[16];
    const int fg3 = flags[25], fbe3 = flags[26];

    if (tid < K_) idxs[tid] = idxn[bn*K_ + tid];
    __syncthreads();

    const u16* hVb = wsVn + (size_t)b*N_*H_;
    for (int u = tid; u < 768; u += 256) {
        const int row = u >> 4, c8 = (u & 15) << 3;
        cp8(&hEs[row*YPAD + c8], hE, ((size_t)bn*K_ + row)*H_ + c8, fHE);
        *(uint4*)&hvnbs[row*YPAD + c8] = *(const uint4*)&hVb[(size_t)idxs[row]*H_ + c8];
    }
    __syncthreads();

    const int l15 = lane & 15, q = lane >> 4, n0 = w*32;

    // GEMM1: C-init from gv11; two half-K passes over the split X tile.
#pragma unroll 1
    for (int ct = 0; ct < 2; ct++) {
        f32x4 acc[3];
        const float g = gv11f[(size_t)bn*H_ + n0 + ct*16 + l15];
        for (int mt=0; mt<3; mt++) for (int r=0; r<4; r++) acc[mt][r] = g;
        mfma3x1<H_, YPAD, CAT_, H_>(hEs,   w11t, tid, ct, acc);   // W11 rows 128..255
        mfma3x1<H_, YPAD, CAT_, 2*H_>(hvnbs, w11t, tid, ct, acc); // W11 rows 256..383
        epi_gelu1<false>(acc, nullptr, 0, Y1s, tid, ct);
    }
    __syncthreads();

    u16* Y2s = hvnbs;                 // hv_nb dead after GEMM1
#pragma unroll 1
    for (int ct = 0; ct < 2; ct++) {
        f32x4 acc[3] = {fzero(), fzero(), fzero()};
        mfma3x1<H_, YPAD, H_, 0>(Y1s, w12t, tid, ct, acc);
        epi_gelu1<true>(acc, b12, fb12, Y2s, tid, ct);
    }
    __syncthreads();                  // Y2 visible; ALL Y1s reads done -> Y1s reusable

    float* Ms0 = (float*)Y1s;         // fp32 [48][MSP], cols c with (c>>4) even
    {
        f32x4 accA[3] = {fzero(), fzero(), fzero()};
        mfma3x1<H_, YPAD, H_, 0>(Y2s, w13t, tid, 0, accA);
        const float bvA = ldf(b13, n0 + l15, fb13);
        const int ci = w*16 + l15;
        for (int mt=0; mt<3; mt++)
            for (int r=0; r<4; r++)
                Ms0[(mt*16 + q*4 + r)*MSP + ci] = accA[mt][r] + bvA;
    }
    {
        f32x4 accB[3] = {fzero(), fzero(), fzero()};
        mfma3x1<H_, YPAD, H_, 0>(Y2s, w13t, tid, 1, accB);
        __syncthreads();              // all Y2 (hvnbs) reads done -> hvnbs reusable
        float* Ms1 = (float*)hvnbs;   // fp32 [48][MSP], cols c with (c>>4) odd
        const float bvB = ldf(b13, n0 + 16 + l15, fb13);
        const int ci = w*16 + l15;
        for (int mt=0; mt<3; mt++)
            for (int r=0; r<4; r++)
                Ms1[(mt*16 + q*4 + r)*MSP + ci] = accB[mt][r] + bvB;
    }
    __syncthreads();                  // Ms0 + Ms1 visible

    // h_En = LN(h_E + M), one wave per row; hE from the PRESERVED LDS tile.
    {
        const float* Ms0c = (const float*)Y1s;
        const float* Ms1c = (const float*)hvnbs;
        const int g0  = lane >> 4;
        const int ci0 = (g0 >> 1)*16 + (lane & 15);   // in-tile col for c=lane
        const int ci1 = ci0 + 32;                     // in-tile col for c=lane+64
        const float* Mt = (g0 & 1) ? Ms1c : Ms0c;
        const float gg0 = ldf(g3, lane, fg3),   gg1 = ldf(g3, lane+64, fg3);
        const float bb0 = ldf(be3, lane, fbe3), bb1 = ldf(be3, lane+64, fbe3);
        for (int row = w; row < K_; row += 4) {
            const size_t e0 = ((size_t)bn*K_ + row)*H_;
            float v0 = bf2f(hEs[row*YPAD + lane])      + Mt[row*MSP + ci0];
            float v1 = bf2f(hEs[row*YPAD + lane + 64]) + Mt[row*MSP + ci1];
            float s = v0+v1, ss = v0*v0+v1*v1;
            for (int off=32; off>0; off>>=1) { s += __shfl_xor(s,off); ss += __shfl_xor(ss,off); }
            const float m = s*(1.f/H_);
            const float rstd = rsqrtf(ss*(1.f/H_) - m*m + EPS_);
            outE[e0 + lane]      = (v0-m)*rstd*gg0 + bb0;
            outE[e0 + lane + 64] = (v1-m)*rstd*gg1 + bb1;
        }
    }
}

extern "C" void kernel_launch(void* const* d_in, const int* in_sizes, int n_in,
                              void* d_out, int out_size, void* d_ws, size_t ws_size,
                              hipStream_t stream)
{
    const void* hV      = d_in[0];
    const void* hE      = d_in[1];
    const void* maskV   = d_in[3];
    const void* maskAtt = d_in[4];
    const void* W1b  = d_in[6];
    const void* W2b  = d_in[8];
    const void* W3b  = d_in[10];
    const void* W11b = d_in[12];
    const void* W12b = d_in[14];
    const void* W13b = d_in[16];
    const void* Winb = d_in[18];
    const void* Woutb= d_in[20];
    const void* ln1g = d_in[21]; const void* ln1b = d_in[22];
    const void* ln2g = d_in[23]; const void* ln2b = d_in[24];
    const void* ln3g = d_in[25]; const void* ln3b = d_in[26];

    // ws layout (u16 units) — mirrored inside mega_prep
    u16* ws    = (u16*)d_ws;
    u16* w1t   = ws;                        // 128*384
    u16* w2t   = w1t   + 128*384;           // 128*128
    u16* w3t   = w2t   + 128*128;
    u16* w11t  = w3t   + 128*128;           // 128*384
    u16* w12t  = w11t  + 128*384;
    u16* w13t  = w12t  + 128*128;
    u16* wintt = w13t  + 128*128;           // 512*128
    u16* woutt = wintt + 512*128;           // 128*512
    int* idxn  = (int*)(woutt + 128*512);   // 98304 int32
    u16* wsVn  = (u16*)(idxn + B_*N_*K_);   // 262144 bf16
    float* gv1f  = (float*)(wsVn + B_*N_*H_);   // 262144 f32
    float* hvn1f = gv1f  + (size_t)B_*N_*H_;    // 262144 f32
    float* gv11f = hvn1f + (size_t)B_*N_*H_;    // 262144 f32
    int* flags = (int*)(gv11f + (size_t)B_*N_*H_);  // 27 ints

    Ptrs27 P;
    for (int i = 0; i < 27; i++) { P.p[i] = d_in[i]; P.n[i] = in_sizes[i]; }

    // ONE prep launch: repacks (blocks 0..71, 64x64 transpose tiles) +
    // prep_idx (72..455) + probes (456..482)
    hipLaunchKernelGGL(mega_prep, dim3(483), dim3(256), 0, stream, P, ws, flags);

    float* outV = (float*)d_out;
    float* outE = outV + (size_t)B_*N_*H_;

    hipLaunchKernelGGL(pre_gv1, dim3(B_*N_/16), dim3(256), 0, stream,
                       hV, w1t, W1b, flags, gv1f);
    hipLaunchKernelGGL(node_mfma, dim3(B_*N_), dim3(256), 0, stream,
                       hV, hE, idxn, maskAtt,
                       w1t, w2t, W2b, w3t, W3b,
                       ln1g, ln1b, gv1f, flags, hvn1f);
    hipLaunchKernelGGL(ffn_fused, dim3(B_*N_/16), dim3(256), 0, stream,
                       hvn1f, maskV, wintt, Winb, woutt, Woutb,
                       w11t, W11b, ln2g, ln2b, flags, outV, wsVn, gv11f);
    hipLaunchKernelGGL(edge_mfma, dim3(B_*N_), dim3(256), 0, stream,
                       wsVn, hE, idxn,
                       w11t, w12t, W12b, w13t, W13b,
                       ln3g, ln3b, gv11f, flags, outE);
}